// Round 16
// baseline (2319.070 us; speedup 1.0000x reference)
//
#include <hip/hip_runtime.h>
#include <math.h>

typedef float v2f __attribute__((ext_vector_type(2)));
typedef float v4f __attribute__((ext_vector_type(4)));

__device__ __forceinline__ float hsum(v2f a) { return a.x + a.y; }
__device__ __forceinline__ float rsq_(float x) { return __builtin_amdgcn_rsqf(fmaxf(x, 1e-16f)); }
__device__ __forceinline__ float rcp_(float x) { return __builtin_amdgcn_rcpf(x); }

__device__ __forceinline__ void pk4(v2f& acc, v4f a, v4f b) {
    acc += a.xy * b.xy;
    acc += a.zw * b.zw;
}

// ---- DPP wave-wide reductions (VALU, no LDS pipe). CTRL must be immediate.
template<int CTRL>
__device__ __forceinline__ float dpp_add_(float x) {
    int r = __builtin_amdgcn_update_dpp(0, __float_as_int(x), CTRL, 0xF, 0xF, true);
    return x + __int_as_float(r);
}
template<int CTRL>
__device__ __forceinline__ float dpp_max_(float x) {
    int r = __builtin_amdgcn_update_dpp(__float_as_int(x), __float_as_int(x), CTRL, 0xF, 0xF, false);
    return fmaxf(x, __int_as_float(r));
}
__device__ __forceinline__ float dpp_sum64(float x) {
    x = dpp_add_<0x111>(x);   // row_shr:1
    x = dpp_add_<0x112>(x);   // row_shr:2
    x = dpp_add_<0x114>(x);   // row_shr:4
    x = dpp_add_<0x118>(x);   // row_shr:8
    x = dpp_add_<0x142>(x);   // row_bcast15
    x = dpp_add_<0x143>(x);   // row_bcast31
    return __int_as_float(__builtin_amdgcn_readlane(__float_as_int(x), 63));
}
__device__ __forceinline__ float dpp_max64(float x) {
    x = dpp_max_<0x111>(x);
    x = dpp_max_<0x112>(x);
    x = dpp_max_<0x114>(x);
    x = dpp_max_<0x118>(x);
    x = dpp_max_<0x142>(x);
    x = dpp_max_<0x143>(x);
    return __int_as_float(__builtin_amdgcn_readlane(__float_as_int(x), 63));
}

// ============================ Kernel 1: dense phase ============================
// One wave per batch. lane = output dim. DS-traffic-minimized:
//  - content rows read ONCE in a fused triple matmul (ante | n1=c@Wc1^T | P=c@Wc2^T)
//  - matched never materialized: nf = n1 + ms @ P   (P register-resident)
// Stages into d_out's per-batch S slot:
//   out[b*2048 + k*64 + d] = new_fact ; out[b*2048+1024+l] = fire|dconf|1/||cand||
//   out[B*2048 + b] = best_derived_conf
__global__ __launch_bounds__(128, 2)
void dense_kernel(const float* __restrict__ content,   // [B,16,64]
                  const float* __restrict__ types,     // [B,16,3]
                  const float* __restrict__ conf,      // [B,16]
                  const float* __restrict__ W_ante,    // [64,64]
                  const float* __restrict__ W_cons,    // [64,128]
                  const float* __restrict__ lft,       // [1]
                  float* __restrict__ out, int B)
{
    const int l = threadIdx.x & 63;
    const int w = threadIdx.x >> 6;
    const int b = blockIdx.x * 2 + w;
    if (b >= B) return;

    __shared__ float s_cont[2][16*68];   // content -> later new_fact
    __shared__ float s_scr [2][16*68];   // ante
    __shared__ float s_ms  [2][16*20];   // match_scores
    __shared__ float s_sm  [2][96];      // conf@0 pf@16 pr@32 rcn@48 ran@64
    float* cont = s_cont[w];
    float* scr  = s_scr[w];
    float* ms   = s_ms[w];
    float* sm   = s_sm[w];

    const float thr = expf(lft[0]);

    // load content -> LDS; conf/types
    const float* cb = content + ((size_t)b << 10);
    #pragma unroll
    for (int k = 0; k < 16; k++) cont[k*68 + l] = cb[(k << 6) + l];
    if (l < 16) {
        sm[0  + l] = conf[((size_t)b << 4) + l];
        sm[16 + l] = types[(((size_t)b << 4) + l)*3 + 0];   // p_fact
        sm[32 + l] = types[(((size_t)b << 4) + l)*3 + 1];   // p_rule
    }

    // content inverse norms -> sm[48+k]
    {
        const int k = l & 15, q = l >> 4;
        const v4f* row = (const v4f*)&cont[k*68 + q*16];
        v2f s2 = {0.f, 0.f};
        #pragma unroll
        for (int i = 0; i < 4; i++) { v4f v = row[i]; pk4(s2, v, v); }
        float s = hsum(s2);
        s += __shfl_xor(s, 16, 64);
        s += __shfl_xor(s, 32, 64);
        if (l < 16) sm[48 + l] = rsq_(s);
    }

    // ---- PASS A: fused triple matmul over content rows (read once) ----
    // two d-halves to bound register pressure (~96 W regs + 48 accumulators)
    float anteAcc[16], n1[16], p[16];
    #pragma unroll
    for (int hf = 0; hf < 2; hf++) {
        v2f wa[16], w1h[16], w2h[16];
        {
            const v4f* wrA = (const v4f*)(W_ante + ((size_t)l << 6) + hf*32);
            const v4f* wr1 = (const v4f*)(W_cons + ((size_t)l << 7) + hf*32);
            const v4f* wr2 = (const v4f*)(W_cons + ((size_t)l << 7) + 64 + hf*32);
            #pragma unroll
            for (int i = 0; i < 8; i++) {
                v4f va = wrA[i]; wa[2*i]  = va.xy; wa[2*i+1]  = va.zw;
                v4f v1 = wr1[i]; w1h[2*i] = v1.xy; w1h[2*i+1] = v1.zw;
                v4f v2 = wr2[i]; w2h[2*i] = v2.xy; w2h[2*i+1] = v2.zw;
            }
        }
        #pragma unroll
        for (int k = 0; k < 16; k++) {
            const v4f* cr = (const v4f*)&cont[k*68 + hf*32];
            v2f aA = {0,0}, a1 = {0,0}, a2 = {0,0};
            #pragma unroll
            for (int i = 0; i < 8; i++) {
                v4f v = cr[i];
                aA += v.xy*wa[2*i];   aA += v.zw*wa[2*i+1];
                a1 += v.xy*w1h[2*i];  a1 += v.zw*w1h[2*i+1];
                a2 += v.xy*w2h[2*i];  a2 += v.zw*w2h[2*i+1];
            }
            if (hf == 0) { anteAcc[k] = hsum(aA); n1[k] = hsum(a1); p[k] = hsum(a2); }
            else         { anteAcc[k] += hsum(aA); n1[k] += hsum(a1); p[k] += hsum(a2); }
        }
    }
    #pragma unroll
    for (int k = 0; k < 16; k++) scr[k*68 + l] = anteAcc[k];

    // ante inverse norms -> sm[64+k]
    {
        const int k = l & 15, q = l >> 4;
        const v4f* row = (const v4f*)&scr[k*68 + q*16];
        v2f s2 = {0.f, 0.f};
        #pragma unroll
        for (int i = 0; i < 4; i++) { v4f v = row[i]; pk4(s2, v, v); }
        float s = hsum(s2);
        s += __shfl_xor(s, 16, 64);
        s += __shfl_xor(s, 32, 64);
        if (l < 16) sm[64 + l] = rsq_(s);
    }

    // dots + match_scores: lane -> (k = l&15, 4 j's); sim = dot * ran * rcn * pf
    {
        const int k = l & 15, jg4 = (l >> 4) * 4;
        const v4f* ar = (const v4f*)&scr[k*68];
        const v4f* c0 = (const v4f*)&cont[(jg4+0)*68];
        const v4f* c1 = (const v4f*)&cont[(jg4+1)*68];
        const v4f* c2 = (const v4f*)&cont[(jg4+2)*68];
        const v4f* c3 = (const v4f*)&cont[(jg4+3)*68];
        v2f d0 = {0,0}, d1 = {0,0}, d2 = {0,0}, d3 = {0,0};
        #pragma unroll
        for (int i = 0; i < 16; i++) {
            v4f a = ar[i];
            v4f x0 = c0[i]; d0 += a.xy*x0.xy; d0 += a.zw*x0.zw;
            v4f x1 = c1[i]; d1 += a.xy*x1.xy; d1 += a.zw*x1.zw;
            v4f x2 = c2[i]; d2 += a.xy*x2.xy; d2 += a.zw*x2.zw;
            v4f x3 = c3[i]; d3 += a.xy*x3.xy; d3 += a.zw*x3.zw;
        }
        const float ra = sm[64 + k];
        v4f res;
        res.x = hsum(d0) * ra * sm[48 + jg4+0] * sm[16 + jg4+0];
        res.y = hsum(d1) * ra * sm[48 + jg4+1] * sm[16 + jg4+1];
        res.z = hsum(d2) * ra * sm[48 + jg4+2] * sm[16 + jg4+2];
        res.w = hsum(d3) * ra * sm[48 + jg4+3] * sm[16 + jg4+3];
        *(v4f*)&ms[k*20 + jg4] = res;
    }

    // match_strength -> fire / dconf (lanes 0..15) -> staging + tail
    float dc_l = 0.f;
    if (l < 16) {
        const v4f* mr = (const v4f*)&ms[l*20];
        const v4f* cf = (const v4f*)&sm[0];
        v2f st = {0.f, 0.f};
        #pragma unroll
        for (int i = 0; i < 4; i++) { v4f m4 = mr[i]; v4f f4 = cf[i]; st += m4.xy*f4.xy; st += m4.zw*f4.zw; }
        float str = hsum(st);
        float fire = sm[32 + l] * rcp_(1.0f + __expf(-(str - thr) * 2.0f));
        float dcf  = fire * sm[0 + l];
        out[((size_t)b << 11) + 1024 + l] = fire;
        out[((size_t)b << 11) + 1040 + l] = dcf;
        dc_l = dcf;
    }
    {
        float mv = dc_l;
        mv = fmaxf(mv, __shfl_xor(mv, 1, 64));
        mv = fmaxf(mv, __shfl_xor(mv, 2, 64));
        mv = fmaxf(mv, __shfl_xor(mv, 4, 64));
        mv = fmaxf(mv, __shfl_xor(mv, 8, 64));
        if (l == 0) out[((size_t)B << 11) + b] = mv;
    }

    // nf[k] = n1[k] + sum_j ms[k][j] * p[j]   (ms rows broadcast; p in regs)
    float nf[16];
    #pragma unroll
    for (int k = 0; k < 16; k++) {
        const v4f* mr = (const v4f*)&ms[k*20];
        v2f a = {0.f, 0.f};
        #pragma unroll
        for (int i = 0; i < 4; i++) {
            v4f m4 = mr[i];
            v2f plo = {p[4*i+0], p[4*i+1]};
            v2f phi = {p[4*i+2], p[4*i+3]};
            a += m4.xy*plo; a += m4.zw*phi;
        }
        nf[k] = n1[k] + hsum(a);
    }

    // nf -> LDS (for norms) + global staging
    #pragma unroll
    for (int k = 0; k < 16; k++) {
        cont[k*68 + l] = nf[k];
        out[((size_t)b << 11) + (k << 6) + l] = nf[k];
    }

    // 1/||cand|| -> staging
    {
        const int k = l & 15, q = l >> 4;
        const v4f* row = (const v4f*)&cont[k*68 + q*16];
        v2f s2 = {0.f, 0.f};
        #pragma unroll
        for (int i = 0; i < 4; i++) { v4f v = row[i]; pk4(s2, v, v); }
        float s = hsum(s2);
        s += __shfl_xor(s, 16, 64);
        s += __shfl_xor(s, 32, 64);
        if (l < 16) out[((size_t)b << 11) + 1056 + l] = rsq_(s);
    }
}

// ============================ Kernel 2: sequential scan ============================
// (unchanged from round 15: 8 batches/block of 512, S in regs (m,h) layout,
//  W1 block-shared transposed v4f, DPP softmax reductions)
__global__ __launch_bounds__(512, 4)
void scan_kernel(const float* __restrict__ Sg,      // [B,32,64]
                 const float* __restrict__ W_gw,    // [64,128]
                 const float* __restrict__ W_gb,    // [64]
                 float* __restrict__ out, int B)
{
    const int t = threadIdx.x;
    const int l = t & 63;
    const int w = t >> 6;                 // wave 0..7
    const int b = (blockIdx.x << 3) + w;  // batch

    __shared__ v4f            w1v[1024];         // w1v[i*64+j] = W1[j][4i..4i+3]
    __shared__ float          snf_  [8][16*64];  // new_fact rows
    __shared__ unsigned short gcB_  [8][16*64];  // bf16 gamma cand-half [k][l]
    __shared__ float          smeta_[8][48];     // fire[16] dconf[16] 1/||cand||[16]
    __shared__ float          bsb_  [8][68];     // best-slot row (d-layout)
    __shared__ float          ncb_  [8][68];     // new_content (d-layout)
    float* snf   = snf_[w];
    unsigned short* gcB = gcB_[w];
    float* smeta = smeta_[w];
    float* bsb   = bsb_[w];
    float* ncb   = ncb_[w];

    const int m = l & 31, h = l >> 5;

    // block-cooperative W1 -> LDS (transposed v4f layout)
    {
        #pragma unroll
        for (int j = 0; j < 2; j++) {
            const int i = (w << 1) + j;
            w1v[i*64 + l] = *(const v4f*)&W_gw[(size_t)l*128 + i*4];
        }
    }

    v2f Sreg[16];

    if (b < B) {
        if (l < 48) smeta[l] = out[((size_t)b << 11) + 1024 + l];

        const float* nfb = out + ((size_t)b << 11);
        #pragma unroll
        for (int i = 0; i < 4; i++) {
            *(v4f*)&snf[i*256 + l*4] = *(const v4f*)&nfb[i*256 + l*4];
        }

        {
            const float* srow = Sg + ((size_t)b << 11) + (m << 6) + (h << 5);
            #pragma unroll
            for (int i = 0; i < 8; i++) {
                v4f v = *(const v4f*)&srow[i*4];
                Sreg[2*i]   = v.xy;
                Sreg[2*i+1] = v.zw;
            }
        }

        // gc[k][l] = cand_k . W_gw[l][64:128]  (wB transient)
        {
            v2f wB[32];
            const v4f* w2 = (const v4f*)(W_gw + ((size_t)l << 7) + 64);
            #pragma unroll
            for (int i = 0; i < 16; i++) { v4f v = w2[i]; wB[2*i] = v.xy; wB[2*i+1] = v.zw; }
            #pragma unroll
            for (int k = 0; k < 16; k++) {
                const v4f* cr = (const v4f*)&snf[k << 6];
                v2f a = {0.f, 0.f};
                #pragma unroll
                for (int i = 0; i < 16; i++) { v4f v = cr[i]; a += v.xy*wB[2*i]; a += v.zw*wB[2*i+1]; }
                const float g = hsum(a);
                gcB[(k << 6) + l] = (unsigned short)((__float_as_uint(g) + 0x8000u) >> 16);
            }
        }
    }

    __syncthreads();          // w1v visible to all waves
    if (b >= B) return;

    const float gb = W_gb[l];

    #pragma unroll 1
    for (int k = 0; k < 16; k++) {
        const float fire = smeta[k];          // wave-uniform
        if (fire <= 0.1f) continue;
        const float dck  = smeta[16 + k];
        const float rncn = smeta[32 + k];     // 1/||cand||
        const float gck  = __uint_as_float((unsigned)gcB[(k << 6) + l] << 16);
        const float cd   = snf[(k << 6) + l]; // cand[l], per-lane

        // dot[m] = cand.S[m] and ||S[m]||^2 -- registers + broadcast cand
        v2f d2 = {0.f, 0.f}, n2 = {0.f, 0.f};
        {
            const v4f* cr = (const v4f*)&snf[(k << 6) + (h << 5)];
            #pragma unroll
            for (int i = 0; i < 8; i++) {
                v4f c = cr[i];
                d2 += Sreg[2*i]*c.xy;       d2 += Sreg[2*i+1]*c.zw;
                n2 += Sreg[2*i]*Sreg[2*i];  n2 += Sreg[2*i+1]*Sreg[2*i+1];
            }
        }
        float dt = hsum(d2);
        float nn = hsum(n2);
        dt += __shfl_xor(dt, 32, 64);
        nn += __shfl_xor(nn, 32, 64);
        const float sc = dt * rsq_(nn) * rncn;
        const float e  = __expf(4.0f * sc);

        // argmax via DPP max + ballot; first index on ties
        const float mx = dpp_max64(sc);
        const unsigned long long bal = __ballot(sc == mx);
        const int best = __ffsll(bal & 0xffffffffULL) - 1;   // wave-uniform

        // best-slot row -> bsb early (owning 2 lanes write their halves)
        if (m == best) {
            #pragma unroll
            for (int j = 0; j < 8; j++) {
                v4f v = { Sreg[2*j].x, Sreg[2*j].y, Sreg[2*j+1].x, Sreg[2*j+1].y };
                *(v4f*)&bsb[(h << 5) + j*4] = v;
            }
        }

        // softmax sum via DPP; halves duplicated -> x2
        const float tot = dpp_sum64(e);
        const float wm  = dck * e * 2.0f * rcp_(tot);

        // gamma[l] = sigmoid(bs . W1[l] + gc + gb); W1 from block LDS
        v2f g2 = {0.f, 0.f};
        {
            const v4f* wrow = &w1v[l];
            #pragma unroll
            for (int i = 0; i < 16; i++) {
                v4f bs = *(const v4f*)&bsb[i*4];   // broadcast
                v4f wv = wrow[i*64];               // conflict-free
                g2 += bs.xy*wv.xy; g2 += bs.zw*wv.zw;
            }
        }
        const float g = gb + gck + hsum(g2);
        const float gamma = rcp_(1.0f + __expf(-g));
        const float bsd = bsb[l];
        ncb[l] = gamma*cd + (1.0f - gamma)*bsd;

        // update own half-row: S[m][d] += wm * (ncd[d] - S[m][d])
        const v2f wm2 = {wm, wm};
        {
            const v4f* nr = (const v4f*)&ncb[h << 5];
            #pragma unroll
            for (int i = 0; i < 8; i++) {
                v4f nc = nr[i];
                Sreg[2*i]   += wm2 * (nc.xy - Sreg[2*i]);
                Sreg[2*i+1] += wm2 * (nc.zw - Sreg[2*i+1]);
            }
        }
    }

    // store S_new from regs (overwrites staging region)
    {
        float* ob = out + ((size_t)b << 11) + (m << 6) + (h << 5);
        #pragma unroll
        for (int j = 0; j < 8; j++) {
            v4f v = { Sreg[2*j].x, Sreg[2*j].y, Sreg[2*j+1].x, Sreg[2*j+1].y };
            *(v4f*)&ob[j*4] = v;
        }
    }
}

extern "C" void kernel_launch(void* const* d_in, const int* in_sizes, int n_in,
                              void* d_out, int out_size, void* d_ws, size_t ws_size,
                              hipStream_t stream) {
    const float* content = (const float*)d_in[0];
    const float* types   = (const float*)d_in[1];
    const float* conf    = (const float*)d_in[2];
    const float* S       = (const float*)d_in[3];
    const float* W_ante  = (const float*)d_in[4];
    const float* W_cons  = (const float*)d_in[5];
    const float* W_gw    = (const float*)d_in[6];
    const float* W_gb    = (const float*)d_in[7];
    const float* lft     = (const float*)d_in[8];

    const int B = in_sizes[0] / 1024;

    hipLaunchKernelGGL(dense_kernel, dim3((B + 1) / 2), dim3(128), 0, stream,
                       content, types, conf, W_ante, W_cons, lft, (float*)d_out, B);
    hipLaunchKernelGGL(scan_kernel, dim3((B + 7) / 8), dim3(512), 0, stream,
                       S, W_gw, W_gb, (float*)d_out, B);
}

// Round 17
// 237.672 us; speedup vs baseline: 9.7574x; 9.7574x over previous
//
#include <hip/hip_runtime.h>
#include <math.h>

typedef float v2f __attribute__((ext_vector_type(2)));
typedef float v4f __attribute__((ext_vector_type(4)));
typedef short bs8 __attribute__((ext_vector_type(8)));   // 8 bf16 (4 VGPRs)

__device__ __forceinline__ float hsum(v2f a) { return a.x + a.y; }
__device__ __forceinline__ float rsq_(float x) { return __builtin_amdgcn_rsqf(fmaxf(x, 1e-16f)); }
__device__ __forceinline__ float rcp_(float x) { return __builtin_amdgcn_rcpf(x); }

__device__ __forceinline__ void pk4(v2f& acc, v4f a, v4f b) {
    acc += a.xy * b.xy;
    acc += a.zw * b.zw;
}

__device__ __forceinline__ short bf16rne_(float x) {
    unsigned u = __float_as_uint(x);
    return (short)((u + 0x7FFFu + ((u >> 16) & 1)) >> 16);
}

// ---- DPP wave-wide reductions (VALU, no LDS pipe). CTRL must be immediate.
template<int CTRL>
__device__ __forceinline__ float dpp_add_(float x) {
    int r = __builtin_amdgcn_update_dpp(0, __float_as_int(x), CTRL, 0xF, 0xF, true);
    return x + __int_as_float(r);
}
template<int CTRL>
__device__ __forceinline__ float dpp_max_(float x) {
    int r = __builtin_amdgcn_update_dpp(__float_as_int(x), __float_as_int(x), CTRL, 0xF, 0xF, false);
    return fmaxf(x, __int_as_float(r));
}
__device__ __forceinline__ float dpp_sum64(float x) {
    x = dpp_add_<0x111>(x);
    x = dpp_add_<0x112>(x);
    x = dpp_add_<0x114>(x);
    x = dpp_add_<0x118>(x);
    x = dpp_add_<0x142>(x);
    x = dpp_add_<0x143>(x);
    return __int_as_float(__builtin_amdgcn_readlane(__float_as_int(x), 63));
}
__device__ __forceinline__ float dpp_max64(float x) {
    x = dpp_max_<0x111>(x);
    x = dpp_max_<0x112>(x);
    x = dpp_max_<0x114>(x);
    x = dpp_max_<0x118>(x);
    x = dpp_max_<0x142>(x);
    x = dpp_max_<0x143>(x);
    return __int_as_float(__builtin_amdgcn_readlane(__float_as_int(x), 63));
}

// ============================ Kernel 1: dense phase (MFMA) ============================
// 4 batches per 256-thread block (1 wave each). Weight matmuls (ante, new_fact)
// run on matrix cores in bf16 (error ~2e-3 abs, vs 0.107 threshold); cosine
// dots / softmax / fire stay exact f32. B-fragments packed once per block.
// MFMA layout: A[m=l&15][k=(l>>4)*8+e]; B[k=(l>>4)*8+e][n=l&15]; D: n=l&15, m=(l>>4)*4+r.
__global__ __launch_bounds__(256, 2)
void dense_kernel(const float* __restrict__ content,   // [B,16,64]
                  const float* __restrict__ types,     // [B,16,3]
                  const float* __restrict__ conf,      // [B,16]
                  const float* __restrict__ W_ante,    // [64,64]
                  const float* __restrict__ W_cons,    // [64,128]
                  const float* __restrict__ lft,       // [1]
                  float* __restrict__ out, int B)
{
    const int tid = threadIdx.x;
    const int l = tid & 63;
    const int w = tid >> 6;
    const int b = blockIdx.x * 4 + w;

    __shared__ float s_cont[4][16*68];   // content rows
    __shared__ float s_scr [4][16*68];   // ante -> later matched
    __shared__ float s_ms  [4][16*20];   // match_scores
    __shared__ float s_sm  [4][96];      // conf@0 pf@16 pr@32 rcn@48 ran@64
    __shared__ bs8   s_bA[512];          // B-frags: W_ante   [t*2+s][lane]
    __shared__ bs8   s_b1[512];          // B-frags: W_cons[:, 0:64]
    __shared__ bs8   s_b2[512];          // B-frags: W_cons[:,64:128]

    // -------- cooperative B-fragment pack (once per block) --------
    #pragma unroll
    for (int it = 0; it < 6; it++) {
        const int fid = tid + it*256;           // 0..1535
        const int mat = fid >> 9, rem = fid & 511;
        const int fl  = rem & 63;
        const int row = ((rem >> 7) & 3)*16 + (fl & 15);   // ts>>1 = tile
        const int kb  = ((rem >> 6) & 1)*32 + (fl >> 4)*8; // ts&1 = kstep
        const float* src = (mat == 0) ? (W_ante + row*64 + kb)
                                      : (W_cons + row*128 + kb + ((mat == 2) ? 64 : 0));
        bs8 v;
        #pragma unroll
        for (int e = 0; e < 8; e++) v[e] = bf16rne_(src[e]);
        bs8* dst = (mat == 0) ? s_bA : (mat == 1) ? s_b1 : s_b2;
        dst[rem] = v;
    }
    __syncthreads();
    if (b >= B) return;

    float* cont = s_cont[w];
    float* scr  = s_scr[w];
    float* ms   = s_ms[w];
    float* sm   = s_sm[w];

    const float thr = expf(lft[0]);

    // load content (regs + LDS), conf/types
    float c[16];
    const float* cb = content + ((size_t)b << 10);
    #pragma unroll
    for (int k = 0; k < 16; k++) {
        float v = cb[(k << 6) + l];
        c[k] = v;
        cont[k*68 + l] = v;
    }
    if (l < 16) {
        sm[0  + l] = conf[((size_t)b << 4) + l];
        sm[16 + l] = types[(((size_t)b << 4) + l)*3 + 0];   // p_fact
        sm[32 + l] = types[(((size_t)b << 4) + l)*3 + 1];   // p_rule
    }

    // content inverse norms -> sm[48+k]
    {
        const int k = l & 15, q = l >> 4;
        const v4f* row = (const v4f*)&cont[k*68 + q*16];
        v2f s2 = {0.f, 0.f};
        #pragma unroll
        for (int i = 0; i < 4; i++) { v4f v = row[i]; pk4(s2, v, v); }
        float s = hsum(s2);
        s += __shfl_xor(s, 16, 64);
        s += __shfl_xor(s, 32, 64);
        if (l < 16) sm[48 + l] = rsq_(s);
    }

    // A-fragments for content (read own row chunk from LDS, cvt bf16)
    bs8 aC[2];
    #pragma unroll
    for (int s = 0; s < 2; s++) {
        const float* ap = &cont[(l & 15)*68 + s*32 + (l >> 4)*8];
        v4f p0 = *(const v4f*)ap;
        v4f p1 = *(const v4f*)(ap + 4);
        bs8 v;
        v[0]=bf16rne_(p0.x); v[1]=bf16rne_(p0.y); v[2]=bf16rne_(p0.z); v[3]=bf16rne_(p0.w);
        v[4]=bf16rne_(p1.x); v[5]=bf16rne_(p1.y); v[6]=bf16rne_(p1.z); v[7]=bf16rne_(p1.w);
        aC[s] = v;
    }

    // ---- ante = content @ W_ante^T via MFMA; C-layout -> scr rows ----
    #pragma unroll
    for (int t = 0; t < 4; t++) {
        v4f acc = {0.f, 0.f, 0.f, 0.f};
        acc = __builtin_amdgcn_mfma_f32_16x16x32_bf16(aC[0], s_bA[(t*2+0)*64 + l], acc, 0, 0, 0);
        acc = __builtin_amdgcn_mfma_f32_16x16x32_bf16(aC[1], s_bA[(t*2+1)*64 + l], acc, 0, 0, 0);
        #pragma unroll
        for (int r = 0; r < 4; r++)
            scr[((l >> 4)*4 + r)*68 + t*16 + (l & 15)] = acc[r];
    }

    // ante inverse norms -> sm[64+k]
    {
        const int k = l & 15, q = l >> 4;
        const v4f* row = (const v4f*)&scr[k*68 + q*16];
        v2f s2 = {0.f, 0.f};
        #pragma unroll
        for (int i = 0; i < 4; i++) { v4f v = row[i]; pk4(s2, v, v); }
        float s = hsum(s2);
        s += __shfl_xor(s, 16, 64);
        s += __shfl_xor(s, 32, 64);
        if (l < 16) sm[64 + l] = rsq_(s);
    }

    // dots + match_scores (exact f32): lane -> (k = l&15, 4 j's)
    {
        const int k = l & 15, jg4 = (l >> 4) * 4;
        const v4f* ar = (const v4f*)&scr[k*68];
        const v4f* c0 = (const v4f*)&cont[(jg4+0)*68];
        const v4f* c1 = (const v4f*)&cont[(jg4+1)*68];
        const v4f* c2 = (const v4f*)&cont[(jg4+2)*68];
        const v4f* c3 = (const v4f*)&cont[(jg4+3)*68];
        v2f d0 = {0,0}, d1 = {0,0}, d2 = {0,0}, d3 = {0,0};
        #pragma unroll
        for (int i = 0; i < 16; i++) {
            v4f a = ar[i];
            v4f x0 = c0[i]; d0 += a.xy*x0.xy; d0 += a.zw*x0.zw;
            v4f x1 = c1[i]; d1 += a.xy*x1.xy; d1 += a.zw*x1.zw;
            v4f x2 = c2[i]; d2 += a.xy*x2.xy; d2 += a.zw*x2.zw;
            v4f x3 = c3[i]; d3 += a.xy*x3.xy; d3 += a.zw*x3.zw;
        }
        const float ra = sm[64 + k];
        v4f res;
        res.x = hsum(d0) * ra * sm[48 + jg4+0] * sm[16 + jg4+0];
        res.y = hsum(d1) * ra * sm[48 + jg4+1] * sm[16 + jg4+1];
        res.z = hsum(d2) * ra * sm[48 + jg4+2] * sm[16 + jg4+2];
        res.w = hsum(d3) * ra * sm[48 + jg4+3] * sm[16 + jg4+3];
        *(v4f*)&ms[k*20 + jg4] = res;
    }

    // match_strength -> fire / dconf (lanes 0..15) -> staging + tail
    float dc_l = 0.f;
    if (l < 16) {
        const v4f* mr = (const v4f*)&ms[l*20];
        const v4f* cf = (const v4f*)&sm[0];
        v2f st = {0.f, 0.f};
        #pragma unroll
        for (int i = 0; i < 4; i++) { v4f m4 = mr[i]; v4f f4 = cf[i]; st += m4.xy*f4.xy; st += m4.zw*f4.zw; }
        float str = hsum(st);
        float fire = sm[32 + l] * rcp_(1.0f + __expf(-(str - thr) * 2.0f));
        float dcf  = fire * sm[0 + l];
        out[((size_t)b << 11) + 1024 + l] = fire;
        out[((size_t)b << 11) + 1040 + l] = dcf;
        dc_l = dcf;
    }
    {
        float mv = dc_l;
        mv = fmaxf(mv, __shfl_xor(mv, 1, 64));
        mv = fmaxf(mv, __shfl_xor(mv, 2, 64));
        mv = fmaxf(mv, __shfl_xor(mv, 4, 64));
        mv = fmaxf(mv, __shfl_xor(mv, 8, 64));
        if (l == 0) out[((size_t)B << 11) + b] = mv;
    }

    // matched[k][d] = sum_j ms[k][j] * content[j][d]  (exact f32, from regs c[])
    float mt[16];
    #pragma unroll
    for (int k = 0; k < 16; k++) {
        const v4f* mr = (const v4f*)&ms[k*20];
        v2f m2 = {0.f, 0.f};
        #pragma unroll
        for (int i = 0; i < 4; i++) {
            v4f m4 = mr[i];
            v2f clo = {c[4*i+0], c[4*i+1]};
            v2f chi = {c[4*i+2], c[4*i+3]};
            m2 += m4.xy*clo; m2 += m4.zw*chi;
        }
        mt[k] = hsum(m2);
    }
    #pragma unroll
    for (int k = 0; k < 16; k++) scr[k*68 + l] = mt[k];   // ante dead -> matched

    // A-fragments for matched
    bs8 aM[2];
    #pragma unroll
    for (int s = 0; s < 2; s++) {
        const float* ap = &scr[(l & 15)*68 + s*32 + (l >> 4)*8];
        v4f p0 = *(const v4f*)ap;
        v4f p1 = *(const v4f*)(ap + 4);
        bs8 v;
        v[0]=bf16rne_(p0.x); v[1]=bf16rne_(p0.y); v[2]=bf16rne_(p0.z); v[3]=bf16rne_(p0.w);
        v[4]=bf16rne_(p1.x); v[5]=bf16rne_(p1.y); v[6]=bf16rne_(p1.z); v[7]=bf16rne_(p1.w);
        aM[s] = v;
    }

    // ---- nf = content @ Wc1^T + matched @ Wc2^T via chained MFMA ----
    v4f nfacc[4];
    #pragma unroll
    for (int t = 0; t < 4; t++) {
        v4f acc = {0.f, 0.f, 0.f, 0.f};
        acc = __builtin_amdgcn_mfma_f32_16x16x32_bf16(aC[0], s_b1[(t*2+0)*64 + l], acc, 0, 0, 0);
        acc = __builtin_amdgcn_mfma_f32_16x16x32_bf16(aC[1], s_b1[(t*2+1)*64 + l], acc, 0, 0, 0);
        acc = __builtin_amdgcn_mfma_f32_16x16x32_bf16(aM[0], s_b2[(t*2+0)*64 + l], acc, 0, 0, 0);
        acc = __builtin_amdgcn_mfma_f32_16x16x32_bf16(aM[1], s_b2[(t*2+1)*64 + l], acc, 0, 0, 0);
        nfacc[t] = acc;
    }

    // nf staging stores (C-layout: row k=(l>>4)*4+r, col d=t*16+(l&15))
    #pragma unroll
    for (int t = 0; t < 4; t++) {
        #pragma unroll
        for (int r = 0; r < 4; r++) {
            out[((size_t)b << 11) + (size_t)(((l >> 4)*4 + r) << 6) + t*16 + (l & 15)] = nfacc[t][r];
        }
    }

    // 1/||cand|| from C-layout: in-lane sum over t, then reduce across 16 cols
    #pragma unroll
    for (int r = 0; r < 4; r++) {
        float s = 0.f;
        #pragma unroll
        for (int t = 0; t < 4; t++) s += nfacc[t][r]*nfacc[t][r];
        s += __shfl_xor(s, 1, 64);
        s += __shfl_xor(s, 2, 64);
        s += __shfl_xor(s, 4, 64);
        s += __shfl_xor(s, 8, 64);
        if ((l & 15) == 0)
            out[((size_t)b << 11) + 1056 + (l >> 4)*4 + r] = rsq_(s);
    }
}

// ============================ Kernel 2: sequential scan ============================
// (unchanged from round 15: 8 batches/block of 512, S in regs (m,h) layout,
//  W1 block-shared transposed v4f, DPP softmax reductions)
__global__ __launch_bounds__(512, 4)
void scan_kernel(const float* __restrict__ Sg,      // [B,32,64]
                 const float* __restrict__ W_gw,    // [64,128]
                 const float* __restrict__ W_gb,    // [64]
                 float* __restrict__ out, int B)
{
    const int t = threadIdx.x;
    const int l = t & 63;
    const int w = t >> 6;                 // wave 0..7
    const int b = (blockIdx.x << 3) + w;  // batch

    __shared__ v4f            w1v[1024];         // w1v[i*64+j] = W1[j][4i..4i+3]
    __shared__ float          snf_  [8][16*64];  // new_fact rows
    __shared__ unsigned short gcB_  [8][16*64];  // bf16 gamma cand-half [k][l]
    __shared__ float          smeta_[8][48];     // fire[16] dconf[16] 1/||cand||[16]
    __shared__ float          bsb_  [8][68];     // best-slot row (d-layout)
    __shared__ float          ncb_  [8][68];     // new_content (d-layout)
    float* snf   = snf_[w];
    unsigned short* gcB = gcB_[w];
    float* smeta = smeta_[w];
    float* bsb   = bsb_[w];
    float* ncb   = ncb_[w];

    const int m = l & 31, h = l >> 5;

    // block-cooperative W1 -> LDS (transposed v4f layout)
    {
        #pragma unroll
        for (int j = 0; j < 2; j++) {
            const int i = (w << 1) + j;
            w1v[i*64 + l] = *(const v4f*)&W_gw[(size_t)l*128 + i*4];
        }
    }

    v2f Sreg[16];

    if (b < B) {
        if (l < 48) smeta[l] = out[((size_t)b << 11) + 1024 + l];

        const float* nfb = out + ((size_t)b << 11);
        #pragma unroll
        for (int i = 0; i < 4; i++) {
            *(v4f*)&snf[i*256 + l*4] = *(const v4f*)&nfb[i*256 + l*4];
        }

        {
            const float* srow = Sg + ((size_t)b << 11) + (m << 6) + (h << 5);
            #pragma unroll
            for (int i = 0; i < 8; i++) {
                v4f v = *(const v4f*)&srow[i*4];
                Sreg[2*i]   = v.xy;
                Sreg[2*i+1] = v.zw;
            }
        }

        // gc[k][l] = cand_k . W_gw[l][64:128]  (wB transient)
        {
            v2f wB[32];
            const v4f* w2 = (const v4f*)(W_gw + ((size_t)l << 7) + 64);
            #pragma unroll
            for (int i = 0; i < 16; i++) { v4f v = w2[i]; wB[2*i] = v.xy; wB[2*i+1] = v.zw; }
            #pragma unroll
            for (int k = 0; k < 16; k++) {
                const v4f* cr = (const v4f*)&snf[k << 6];
                v2f a = {0.f, 0.f};
                #pragma unroll
                for (int i = 0; i < 16; i++) { v4f v = cr[i]; a += v.xy*wB[2*i]; a += v.zw*wB[2*i+1]; }
                const float g = hsum(a);
                gcB[(k << 6) + l] = (unsigned short)((__float_as_uint(g) + 0x8000u) >> 16);
            }
        }
    }

    __syncthreads();          // w1v visible to all waves
    if (b >= B) return;

    const float gb = W_gb[l];

    #pragma unroll 1
    for (int k = 0; k < 16; k++) {
        const float fire = smeta[k];          // wave-uniform
        if (fire <= 0.1f) continue;
        const float dck  = smeta[16 + k];
        const float rncn = smeta[32 + k];     // 1/||cand||
        const float gck  = __uint_as_float((unsigned)gcB[(k << 6) + l] << 16);
        const float cd   = snf[(k << 6) + l]; // cand[l], per-lane

        // dot[m] = cand.S[m] and ||S[m]||^2 -- registers + broadcast cand
        v2f d2 = {0.f, 0.f}, n2 = {0.f, 0.f};
        {
            const v4f* cr = (const v4f*)&snf[(k << 6) + (h << 5)];
            #pragma unroll
            for (int i = 0; i < 8; i++) {
                v4f c = cr[i];
                d2 += Sreg[2*i]*c.xy;       d2 += Sreg[2*i+1]*c.zw;
                n2 += Sreg[2*i]*Sreg[2*i];  n2 += Sreg[2*i+1]*Sreg[2*i+1];
            }
        }
        float dt = hsum(d2);
        float nn = hsum(n2);
        dt += __shfl_xor(dt, 32, 64);
        nn += __shfl_xor(nn, 32, 64);
        const float sc = dt * rsq_(nn) * rncn;
        const float e  = __expf(4.0f * sc);

        // argmax via DPP max + ballot; first index on ties
        const float mx = dpp_max64(sc);
        const unsigned long long bal = __ballot(sc == mx);
        const int best = __ffsll(bal & 0xffffffffULL) - 1;   // wave-uniform

        // best-slot row -> bsb early (owning 2 lanes write their halves)
        if (m == best) {
            #pragma unroll
            for (int j = 0; j < 8; j++) {
                v4f v = { Sreg[2*j].x, Sreg[2*j].y, Sreg[2*j+1].x, Sreg[2*j+1].y };
                *(v4f*)&bsb[(h << 5) + j*4] = v;
            }
        }

        // softmax sum via DPP; halves duplicated -> x2
        const float tot = dpp_sum64(e);
        const float wm  = dck * e * 2.0f * rcp_(tot);

        // gamma[l] = sigmoid(bs . W1[l] + gc + gb); W1 from block LDS
        v2f g2 = {0.f, 0.f};
        {
            const v4f* wrow = &w1v[l];
            #pragma unroll
            for (int i = 0; i < 16; i++) {
                v4f bs = *(const v4f*)&bsb[i*4];   // broadcast
                v4f wv = wrow[i*64];               // conflict-free
                g2 += bs.xy*wv.xy; g2 += bs.zw*wv.zw;
            }
        }
        const float g = gb + gck + hsum(g2);
        const float gamma = rcp_(1.0f + __expf(-g));
        const float bsd = bsb[l];
        ncb[l] = gamma*cd + (1.0f - gamma)*bsd;

        // update own half-row: S[m][d] += wm * (ncd[d] - S[m][d])
        const v2f wm2 = {wm, wm};
        {
            const v4f* nr = (const v4f*)&ncb[h << 5];
            #pragma unroll
            for (int i = 0; i < 8; i++) {
                v4f nc = nr[i];
                Sreg[2*i]   += wm2 * (nc.xy - Sreg[2*i]);
                Sreg[2*i+1] += wm2 * (nc.zw - Sreg[2*i+1]);
            }
        }
    }

    // store S_new from regs (overwrites staging region)
    {
        float* ob = out + ((size_t)b << 11) + (m << 6) + (h << 5);
        #pragma unroll
        for (int j = 0; j < 8; j++) {
            v4f v = { Sreg[2*j].x, Sreg[2*j].y, Sreg[2*j+1].x, Sreg[2*j+1].y };
            *(v4f*)&ob[j*4] = v;
        }
    }
}

extern "C" void kernel_launch(void* const* d_in, const int* in_sizes, int n_in,
                              void* d_out, int out_size, void* d_ws, size_t ws_size,
                              hipStream_t stream) {
    const float* content = (const float*)d_in[0];
    const float* types   = (const float*)d_in[1];
    const float* conf    = (const float*)d_in[2];
    const float* S       = (const float*)d_in[3];
    const float* W_ante  = (const float*)d_in[4];
    const float* W_cons  = (const float*)d_in[5];
    const float* W_gw    = (const float*)d_in[6];
    const float* W_gb    = (const float*)d_in[7];
    const float* lft     = (const float*)d_in[8];

    const int B = in_sizes[0] / 1024;

    hipLaunchKernelGGL(dense_kernel, dim3((B + 3) / 4), dim3(256), 0, stream,
                       content, types, conf, W_ante, W_cons, lft, (float*)d_out, B);
    hipLaunchKernelGGL(scan_kernel, dim3((B + 7) / 8), dim3(512), 0, stream,
                       S, W_gw, W_gb, (float*)d_out, B);
}

// Round 18
// 216.836 us; speedup vs baseline: 10.6950x; 1.0961x over previous
//
#include <hip/hip_runtime.h>
#include <math.h>

typedef float v2f __attribute__((ext_vector_type(2)));
typedef float v4f __attribute__((ext_vector_type(4)));
typedef short bs8 __attribute__((ext_vector_type(8)));   // 8 bf16 (4 VGPRs)

__device__ __forceinline__ float hsum(v2f a) { return a.x + a.y; }
__device__ __forceinline__ float rsq_(float x) { return __builtin_amdgcn_rsqf(fmaxf(x, 1e-16f)); }
__device__ __forceinline__ float rcp_(float x) { return __builtin_amdgcn_rcpf(x); }

__device__ __forceinline__ void pk4(v2f& acc, v4f a, v4f b) {
    acc += a.xy * b.xy;
    acc += a.zw * b.zw;
}

__device__ __forceinline__ short bf16rne_(float x) {
    unsigned u = __float_as_uint(x);
    return (short)((u + 0x7FFFu + ((u >> 16) & 1)) >> 16);
}
__device__ __forceinline__ float bf2f_(short s) {
    return __uint_as_float((unsigned)(unsigned short)s << 16);
}

// ---- DPP wave-wide reductions (VALU, no LDS pipe). CTRL must be immediate.
template<int CTRL>
__device__ __forceinline__ float dpp_add_(float x) {
    int r = __builtin_amdgcn_update_dpp(0, __float_as_int(x), CTRL, 0xF, 0xF, true);
    return x + __int_as_float(r);
}
template<int CTRL>
__device__ __forceinline__ float dpp_max_(float x) {
    int r = __builtin_amdgcn_update_dpp(__float_as_int(x), __float_as_int(x), CTRL, 0xF, 0xF, false);
    return fmaxf(x, __int_as_float(r));
}
__device__ __forceinline__ float dpp_sum64(float x) {
    x = dpp_add_<0x111>(x);
    x = dpp_add_<0x112>(x);
    x = dpp_add_<0x114>(x);
    x = dpp_add_<0x118>(x);
    x = dpp_add_<0x142>(x);
    x = dpp_add_<0x143>(x);
    return __int_as_float(__builtin_amdgcn_readlane(__float_as_int(x), 63));
}
__device__ __forceinline__ float dpp_max64(float x) {
    x = dpp_max_<0x111>(x);
    x = dpp_max_<0x112>(x);
    x = dpp_max_<0x114>(x);
    x = dpp_max_<0x118>(x);
    x = dpp_max_<0x142>(x);
    x = dpp_max_<0x143>(x);
    return __int_as_float(__builtin_amdgcn_readlane(__float_as_int(x), 63));
}

// ============================ Kernel 1: dense phase (MFMA) ============================
// 4 batches per 256-thread block (1 wave each). ante / new_fact / gc matmuls on
// matrix cores (bf16). Staging into d_out's per-batch S slot:
//   out[b*2048 + k*64 + d]           = new_fact
//   out[b*2048 + 1024 + l]           = fire[16] | dconf[16] | 1/||cand||[16]
//   (ushort*)(out + b*2048 + 1088)   = gc[k][l] bf16   (gc = nf @ W_gw[:,64:]^T)
//   out[B*2048 + b]                  = best_derived_conf
__global__ __launch_bounds__(256, 2)
void dense_kernel(const float* __restrict__ content,   // [B,16,64]
                  const float* __restrict__ types,     // [B,16,3]
                  const float* __restrict__ conf,      // [B,16]
                  const float* __restrict__ W_ante,    // [64,64]
                  const float* __restrict__ W_cons,    // [64,128]
                  const float* __restrict__ W_gw,      // [64,128]
                  const float* __restrict__ lft,       // [1]
                  float* __restrict__ out, int B)
{
    const int tid = threadIdx.x;
    const int l = tid & 63;
    const int w = tid >> 6;
    const int b = blockIdx.x * 4 + w;

    __shared__ float s_cont[4][16*68];   // content rows
    __shared__ float s_scr [4][16*68];   // ante -> matched -> nf rows
    __shared__ float s_ms  [4][16*20];   // match_scores
    __shared__ float s_sm  [4][96];      // conf@0 pf@16 pr@32 rcn@48 ran@64
    __shared__ bs8   s_bA[512];          // B-frags: W_ante
    __shared__ bs8   s_b1[512];          // B-frags: W_cons[:, 0:64]
    __shared__ bs8   s_b2[512];          // B-frags: W_cons[:,64:128]
    __shared__ bs8   s_bG[512];          // B-frags: W_gw [:,64:128]

    // -------- cooperative B-fragment pack (once per block), 4 matrices --------
    #pragma unroll
    for (int it = 0; it < 8; it++) {
        const int fid = tid + it*256;           // 0..2047
        const int mat = fid >> 9, rem = fid & 511;
        const int fl  = rem & 63;
        const int row = ((rem >> 7) & 3)*16 + (fl & 15);
        const int kb  = ((rem >> 6) & 1)*32 + (fl >> 4)*8;
        const float* src = (mat == 0) ? (W_ante + row*64 + kb)
                         : (mat == 1) ? (W_cons + row*128 + kb)
                         : (mat == 2) ? (W_cons + row*128 + 64 + kb)
                         :              (W_gw  + row*128 + 64 + kb);
        bs8 v;
        #pragma unroll
        for (int e = 0; e < 8; e++) v[e] = bf16rne_(src[e]);
        bs8* dst = (mat == 0) ? s_bA : (mat == 1) ? s_b1 : (mat == 2) ? s_b2 : s_bG;
        dst[rem] = v;
    }
    __syncthreads();
    if (b >= B) return;

    float* cont = s_cont[w];
    float* scr  = s_scr[w];
    float* ms   = s_ms[w];
    float* sm   = s_sm[w];

    const float thr = expf(lft[0]);

    // load content (regs + LDS), conf/types
    float c[16];
    const float* cb = content + ((size_t)b << 10);
    #pragma unroll
    for (int k = 0; k < 16; k++) {
        float v = cb[(k << 6) + l];
        c[k] = v;
        cont[k*68 + l] = v;
    }
    if (l < 16) {
        sm[0  + l] = conf[((size_t)b << 4) + l];
        sm[16 + l] = types[(((size_t)b << 4) + l)*3 + 0];   // p_fact
        sm[32 + l] = types[(((size_t)b << 4) + l)*3 + 1];   // p_rule
    }

    // content inverse norms -> sm[48+k]
    {
        const int k = l & 15, q = l >> 4;
        const v4f* row = (const v4f*)&cont[k*68 + q*16];
        v2f s2 = {0.f, 0.f};
        #pragma unroll
        for (int i = 0; i < 4; i++) { v4f v = row[i]; pk4(s2, v, v); }
        float s = hsum(s2);
        s += __shfl_xor(s, 16, 64);
        s += __shfl_xor(s, 32, 64);
        if (l < 16) sm[48 + l] = rsq_(s);
    }

    // A-fragments for content
    bs8 aC[2];
    #pragma unroll
    for (int s = 0; s < 2; s++) {
        const float* ap = &cont[(l & 15)*68 + s*32 + (l >> 4)*8];
        v4f p0 = *(const v4f*)ap;
        v4f p1 = *(const v4f*)(ap + 4);
        bs8 v;
        v[0]=bf16rne_(p0.x); v[1]=bf16rne_(p0.y); v[2]=bf16rne_(p0.z); v[3]=bf16rne_(p0.w);
        v[4]=bf16rne_(p1.x); v[5]=bf16rne_(p1.y); v[6]=bf16rne_(p1.z); v[7]=bf16rne_(p1.w);
        aC[s] = v;
    }

    // ---- ante = content @ W_ante^T via MFMA; C-layout -> scr rows ----
    #pragma unroll
    for (int t = 0; t < 4; t++) {
        v4f acc = {0.f, 0.f, 0.f, 0.f};
        acc = __builtin_amdgcn_mfma_f32_16x16x32_bf16(aC[0], s_bA[(t*2+0)*64 + l], acc, 0, 0, 0);
        acc = __builtin_amdgcn_mfma_f32_16x16x32_bf16(aC[1], s_bA[(t*2+1)*64 + l], acc, 0, 0, 0);
        #pragma unroll
        for (int r = 0; r < 4; r++)
            scr[((l >> 4)*4 + r)*68 + t*16 + (l & 15)] = acc[r];
    }

    // ante inverse norms -> sm[64+k]
    {
        const int k = l & 15, q = l >> 4;
        const v4f* row = (const v4f*)&scr[k*68 + q*16];
        v2f s2 = {0.f, 0.f};
        #pragma unroll
        for (int i = 0; i < 4; i++) { v4f v = row[i]; pk4(s2, v, v); }
        float s = hsum(s2);
        s += __shfl_xor(s, 16, 64);
        s += __shfl_xor(s, 32, 64);
        if (l < 16) sm[64 + l] = rsq_(s);
    }

    // dots + match_scores (exact f32)
    {
        const int k = l & 15, jg4 = (l >> 4) * 4;
        const v4f* ar = (const v4f*)&scr[k*68];
        const v4f* c0 = (const v4f*)&cont[(jg4+0)*68];
        const v4f* c1 = (const v4f*)&cont[(jg4+1)*68];
        const v4f* c2 = (const v4f*)&cont[(jg4+2)*68];
        const v4f* c3 = (const v4f*)&cont[(jg4+3)*68];
        v2f d0 = {0,0}, d1 = {0,0}, d2 = {0,0}, d3 = {0,0};
        #pragma unroll
        for (int i = 0; i < 16; i++) {
            v4f a = ar[i];
            v4f x0 = c0[i]; d0 += a.xy*x0.xy; d0 += a.zw*x0.zw;
            v4f x1 = c1[i]; d1 += a.xy*x1.xy; d1 += a.zw*x1.zw;
            v4f x2 = c2[i]; d2 += a.xy*x2.xy; d2 += a.zw*x2.zw;
            v4f x3 = c3[i]; d3 += a.xy*x3.xy; d3 += a.zw*x3.zw;
        }
        const float ra = sm[64 + k];
        v4f res;
        res.x = hsum(d0) * ra * sm[48 + jg4+0] * sm[16 + jg4+0];
        res.y = hsum(d1) * ra * sm[48 + jg4+1] * sm[16 + jg4+1];
        res.z = hsum(d2) * ra * sm[48 + jg4+2] * sm[16 + jg4+2];
        res.w = hsum(d3) * ra * sm[48 + jg4+3] * sm[16 + jg4+3];
        *(v4f*)&ms[k*20 + jg4] = res;
    }

    // match_strength -> fire / dconf (lanes 0..15) -> staging + tail
    float dc_l = 0.f;
    if (l < 16) {
        const v4f* mr = (const v4f*)&ms[l*20];
        const v4f* cf = (const v4f*)&sm[0];
        v2f st = {0.f, 0.f};
        #pragma unroll
        for (int i = 0; i < 4; i++) { v4f m4 = mr[i]; v4f f4 = cf[i]; st += m4.xy*f4.xy; st += m4.zw*f4.zw; }
        float str = hsum(st);
        float fire = sm[32 + l] * rcp_(1.0f + __expf(-(str - thr) * 2.0f));
        float dcf  = fire * sm[0 + l];
        out[((size_t)b << 11) + 1024 + l] = fire;
        out[((size_t)b << 11) + 1040 + l] = dcf;
        dc_l = dcf;
    }
    {
        float mv = dc_l;
        mv = fmaxf(mv, __shfl_xor(mv, 1, 64));
        mv = fmaxf(mv, __shfl_xor(mv, 2, 64));
        mv = fmaxf(mv, __shfl_xor(mv, 4, 64));
        mv = fmaxf(mv, __shfl_xor(mv, 8, 64));
        if (l == 0) out[((size_t)B << 11) + b] = mv;
    }

    // matched[k][d] (exact f32, from regs c[])
    float mt[16];
    #pragma unroll
    for (int k = 0; k < 16; k++) {
        const v4f* mr = (const v4f*)&ms[k*20];
        v2f m2 = {0.f, 0.f};
        #pragma unroll
        for (int i = 0; i < 4; i++) {
            v4f m4 = mr[i];
            v2f clo = {c[4*i+0], c[4*i+1]};
            v2f chi = {c[4*i+2], c[4*i+3]};
            m2 += m4.xy*clo; m2 += m4.zw*chi;
        }
        mt[k] = hsum(m2);
    }
    #pragma unroll
    for (int k = 0; k < 16; k++) scr[k*68 + l] = mt[k];   // ante dead -> matched

    // A-fragments for matched
    bs8 aM[2];
    #pragma unroll
    for (int s = 0; s < 2; s++) {
        const float* ap = &scr[(l & 15)*68 + s*32 + (l >> 4)*8];
        v4f p0 = *(const v4f*)ap;
        v4f p1 = *(const v4f*)(ap + 4);
        bs8 v;
        v[0]=bf16rne_(p0.x); v[1]=bf16rne_(p0.y); v[2]=bf16rne_(p0.z); v[3]=bf16rne_(p0.w);
        v[4]=bf16rne_(p1.x); v[5]=bf16rne_(p1.y); v[6]=bf16rne_(p1.z); v[7]=bf16rne_(p1.w);
        aM[s] = v;
    }

    // ---- nf = content @ Wc1^T + matched @ Wc2^T via chained MFMA ----
    v4f nfacc[4];
    #pragma unroll
    for (int t = 0; t < 4; t++) {
        v4f acc = {0.f, 0.f, 0.f, 0.f};
        acc = __builtin_amdgcn_mfma_f32_16x16x32_bf16(aC[0], s_b1[(t*2+0)*64 + l], acc, 0, 0, 0);
        acc = __builtin_amdgcn_mfma_f32_16x16x32_bf16(aC[1], s_b1[(t*2+1)*64 + l], acc, 0, 0, 0);
        acc = __builtin_amdgcn_mfma_f32_16x16x32_bf16(aM[0], s_b2[(t*2+0)*64 + l], acc, 0, 0, 0);
        acc = __builtin_amdgcn_mfma_f32_16x16x32_bf16(aM[1], s_b2[(t*2+1)*64 + l], acc, 0, 0, 0);
        nfacc[t] = acc;
    }

    // nf -> scr rows (for gc A-frags) + global staging
    #pragma unroll
    for (int t = 0; t < 4; t++) {
        #pragma unroll
        for (int r = 0; r < 4; r++) {
            const int krow = (l >> 4)*4 + r, dcol = t*16 + (l & 15);
            scr[krow*68 + dcol] = nfacc[t][r];
            out[((size_t)b << 11) + (size_t)(krow << 6) + dcol] = nfacc[t][r];
        }
    }

    // 1/||cand|| from C-layout
    #pragma unroll
    for (int r = 0; r < 4; r++) {
        float s = 0.f;
        #pragma unroll
        for (int t = 0; t < 4; t++) s += nfacc[t][r]*nfacc[t][r];
        s += __shfl_xor(s, 1, 64);
        s += __shfl_xor(s, 2, 64);
        s += __shfl_xor(s, 4, 64);
        s += __shfl_xor(s, 8, 64);
        if ((l & 15) == 0)
            out[((size_t)b << 11) + 1056 + (l >> 4)*4 + r] = rsq_(s);
    }

    // A-fragments for nf (from scr rows)
    bs8 aN[2];
    #pragma unroll
    for (int s = 0; s < 2; s++) {
        const float* ap = &scr[(l & 15)*68 + s*32 + (l >> 4)*8];
        v4f p0 = *(const v4f*)ap;
        v4f p1 = *(const v4f*)(ap + 4);
        bs8 v;
        v[0]=bf16rne_(p0.x); v[1]=bf16rne_(p0.y); v[2]=bf16rne_(p0.z); v[3]=bf16rne_(p0.w);
        v[4]=bf16rne_(p1.x); v[5]=bf16rne_(p1.y); v[6]=bf16rne_(p1.z); v[7]=bf16rne_(p1.w);
        aN[s] = v;
    }

    // ---- gc = nf @ W_gw[:,64:]^T via MFMA -> bf16 staging ----
    unsigned short* gco = (unsigned short*)(out + ((size_t)b << 11) + 1088);
    #pragma unroll
    for (int t = 0; t < 4; t++) {
        v4f acc = {0.f, 0.f, 0.f, 0.f};
        acc = __builtin_amdgcn_mfma_f32_16x16x32_bf16(aN[0], s_bG[(t*2+0)*64 + l], acc, 0, 0, 0);
        acc = __builtin_amdgcn_mfma_f32_16x16x32_bf16(aN[1], s_bG[(t*2+1)*64 + l], acc, 0, 0, 0);
        #pragma unroll
        for (int r = 0; r < 4; r++)
            gco[(((l >> 4)*4 + r) << 6) + t*16 + (l & 15)] = (unsigned short)bf16rne_(acc[r]);
    }
}

// ============================ Kernel 2: sequential scan ============================
// 8 batches per block of 512 (1 wave each). S in regs (m,h) layout. W1 in LDS as
// bf16 (8 KB, halved stream). gc read from global staging (coalesced, off-chain).
// ncb merged into bsb (in-place). LDS ~43.7 KB -> 3 blocks/CU = 24 waves/CU.
__global__ __launch_bounds__(512, 4)
void scan_kernel(const float* __restrict__ Sg,      // [B,32,64]
                 const float* __restrict__ W_gw,    // [64,128]
                 const float* __restrict__ W_gb,    // [64]
                 float* __restrict__ out, int B)
{
    const int t = threadIdx.x;
    const int l = t & 63;
    const int w = t >> 6;                 // wave 0..7
    const int b = (blockIdx.x << 3) + w;  // batch

    __shared__ bs8   w1b[512];            // bf16 W1: w1b[i*64+j] = W1[j][8i..8i+8)
    __shared__ float snf_  [8][16*64];    // new_fact rows (f32)
    __shared__ float smeta_[8][48];       // fire[16] dconf[16] 1/||cand||[16]
    __shared__ float bsb_  [8][68];       // best-slot row; overwritten with ncd in-place
    float* snf   = snf_[w];
    float* smeta = smeta_[w];
    float* bsb   = bsb_[w];

    const int m = l & 31, h = l >> 5;

    // block-cooperative W1 -> bf16 LDS (one frag per thread)
    {
        const float* src = W_gw + (size_t)(t & 63)*128 + (t >> 6)*8;
        bs8 v;
        #pragma unroll
        for (int e = 0; e < 8; e++) v[e] = bf16rne_(src[e]);
        w1b[(t >> 6)*64 + (t & 63)] = v;
    }

    v2f Sreg[16];

    if (b < B) {
        if (l < 48) smeta[l] = out[((size_t)b << 11) + 1024 + l];

        const float* nfb = out + ((size_t)b << 11);
        #pragma unroll
        for (int i = 0; i < 4; i++) {
            *(v4f*)&snf[i*256 + l*4] = *(const v4f*)&nfb[i*256 + l*4];
        }

        const float* srow = Sg + ((size_t)b << 11) + (m << 6) + (h << 5);
        #pragma unroll
        for (int i = 0; i < 8; i++) {
            v4f v = *(const v4f*)&srow[i*4];
            Sreg[2*i]   = v.xy;
            Sreg[2*i+1] = v.zw;
        }
    }

    __syncthreads();          // w1b visible to all waves
    if (b >= B) return;

    const unsigned short* gcg = (const unsigned short*)(out + ((size_t)b << 11) + 1088);
    const float gb = W_gb[l];

    #pragma unroll 1
    for (int k = 0; k < 16; k++) {
        const float fire = smeta[k];          // wave-uniform
        if (fire <= 0.1f) continue;
        const float dck  = smeta[16 + k];
        const float rncn = smeta[32 + k];     // 1/||cand||
        // issue early (coalesced 128B global, consumed ~400cyc later)
        const unsigned short gcu = gcg[(k << 6) + l];
        const float cd   = snf[(k << 6) + l];

        // dot[m] = cand.S[m] and ||S[m]||^2 -- registers + broadcast cand
        v2f d2 = {0.f, 0.f}, n2 = {0.f, 0.f};
        {
            const v4f* cr = (const v4f*)&snf[(k << 6) + (h << 5)];
            #pragma unroll
            for (int i = 0; i < 8; i++) {
                v4f c = cr[i];
                d2 += Sreg[2*i]*c.xy;       d2 += Sreg[2*i+1]*c.zw;
                n2 += Sreg[2*i]*Sreg[2*i];  n2 += Sreg[2*i+1]*Sreg[2*i+1];
            }
        }
        float dt = hsum(d2);
        float nn = hsum(n2);
        dt += __shfl_xor(dt, 32, 64);
        nn += __shfl_xor(nn, 32, 64);
        const float sc = dt * rsq_(nn) * rncn;
        const float e  = __expf(4.0f * sc);

        // argmax via DPP max + ballot; first index on ties
        const float mx = dpp_max64(sc);
        const unsigned long long bal = __ballot(sc == mx);
        const int best = __ffsll(bal & 0xffffffffULL) - 1;   // wave-uniform

        // best-slot row -> bsb (owning 2 lanes write their halves)
        if (m == best) {
            #pragma unroll
            for (int j = 0; j < 8; j++) {
                v4f v = { Sreg[2*j].x, Sreg[2*j].y, Sreg[2*j+1].x, Sreg[2*j+1].y };
                *(v4f*)&bsb[(h << 5) + j*4] = v;
            }
        }

        // softmax sum via DPP; halves duplicated -> x2
        const float tot = dpp_sum64(e);
        const float wm  = dck * e * 2.0f * rcp_(tot);

        // gamma[l] = sigmoid(bs . W1[l] + gc + gb); W1 bf16 from LDS
        v2f g2 = {0.f, 0.f};
        {
            const bs8* wrow = &w1b[l];
            #pragma unroll
            for (int i = 0; i < 8; i++) {
                bs8 w8 = wrow[i*64];                       // conflict-free b128
                v4f bs0 = *(const v4f*)&bsb[i*8];          // broadcast
                v4f bs1 = *(const v4f*)&bsb[i*8 + 4];      // broadcast
                v2f w01 = {bf2f_(w8[0]), bf2f_(w8[1])};
                v2f w23 = {bf2f_(w8[2]), bf2f_(w8[3])};
                v2f w45 = {bf2f_(w8[4]), bf2f_(w8[5])};
                v2f w67 = {bf2f_(w8[6]), bf2f_(w8[7])};
                g2 += bs0.xy*w01; g2 += bs0.zw*w23;
                g2 += bs1.xy*w45; g2 += bs1.zw*w67;
            }
        }
        const float gck = bf2f_((short)gcu);
        const float g = gb + gck + hsum(g2);
        const float gamma = rcp_(1.0f + __expf(-g));
        const float bsd = bsb[l];
        bsb[l] = gamma*cd + (1.0f - gamma)*bsd;   // ncd, in place (wave-ordered DS)

        // update own half-row: S[m][d] += wm * (ncd[d] - S[m][d])
        const v2f wm2 = {wm, wm};
        {
            const v4f* nr = (const v4f*)&bsb[h << 5];
            #pragma unroll
            for (int i = 0; i < 8; i++) {
                v4f nc = nr[i];
                Sreg[2*i]   += wm2 * (nc.xy - Sreg[2*i]);
                Sreg[2*i+1] += wm2 * (nc.zw - Sreg[2*i+1]);
            }
        }
    }

    // store S_new from regs (overwrites staging region)
    {
        float* ob = out + ((size_t)b << 11) + (m << 6) + (h << 5);
        #pragma unroll
        for (int j = 0; j < 8; j++) {
            v4f v = { Sreg[2*j].x, Sreg[2*j].y, Sreg[2*j+1].x, Sreg[2*j+1].y };
            *(v4f*)&ob[j*4] = v;
        }
    }
}

extern "C" void kernel_launch(void* const* d_in, const int* in_sizes, int n_in,
                              void* d_out, int out_size, void* d_ws, size_t ws_size,
                              hipStream_t stream) {
    const float* content = (const float*)d_in[0];
    const float* types   = (const float*)d_in[1];
    const float* conf    = (const float*)d_in[2];
    const float* S       = (const float*)d_in[3];
    const float* W_ante  = (const float*)d_in[4];
    const float* W_cons  = (const float*)d_in[5];
    const float* W_gw    = (const float*)d_in[6];
    const float* W_gb    = (const float*)d_in[7];
    const float* lft     = (const float*)d_in[8];

    const int B = in_sizes[0] / 1024;

    hipLaunchKernelGGL(dense_kernel, dim3((B + 3) / 4), dim3(256), 0, stream,
                       content, types, conf, W_ante, W_cons, W_gw, lft, (float*)d_out, B);
    hipLaunchKernelGGL(scan_kernel, dim3((B + 7) / 8), dim3(512), 0, stream,
                       S, W_gw, W_gb, (float*)d_out, B);
}

// Round 19
// 204.919 us; speedup vs baseline: 11.3170x; 1.0582x over previous
//
#include <hip/hip_runtime.h>
#include <math.h>

typedef float v2f __attribute__((ext_vector_type(2)));
typedef float v4f __attribute__((ext_vector_type(4)));
typedef short bs8 __attribute__((ext_vector_type(8)));   // 8 bf16 (4 VGPRs)
typedef int   i4  __attribute__((ext_vector_type(4)));

__device__ __forceinline__ float hsum(v2f a) { return a.x + a.y; }
__device__ __forceinline__ float rsq_(float x) { return __builtin_amdgcn_rsqf(fmaxf(x, 1e-16f)); }
__device__ __forceinline__ float rcp_(float x) { return __builtin_amdgcn_rcpf(x); }

__device__ __forceinline__ void pk4(v2f& acc, v4f a, v4f b) {
    acc += a.xy * b.xy;
    acc += a.zw * b.zw;
}

__device__ __forceinline__ short bf16rne_(float x) {
    unsigned u = __float_as_uint(x);
    return (short)((u + 0x7FFFu + ((u >> 16) & 1)) >> 16);
}
__device__ __forceinline__ float bf2f_(short s) {
    return __uint_as_float((unsigned)(unsigned short)s << 16);
}
// pack 2 f32 -> 1 u32 of 2 bf16 (RNE) on the VALU trans pipe
__device__ __forceinline__ int cvtpk_(float lo, float hi) {
    int r;
    asm("v_cvt_pk_bf16_f32 %0, %1, %2" : "=v"(r) : "v"(lo), "v"(hi));
    return r;
}

// ---- DPP wave-wide reductions (VALU, no LDS pipe). CTRL must be immediate.
template<int CTRL>
__device__ __forceinline__ float dpp_add_(float x) {
    int r = __builtin_amdgcn_update_dpp(0, __float_as_int(x), CTRL, 0xF, 0xF, true);
    return x + __int_as_float(r);
}
template<int CTRL>
__device__ __forceinline__ float dpp_max_(float x) {
    int r = __builtin_amdgcn_update_dpp(__float_as_int(x), __float_as_int(x), CTRL, 0xF, 0xF, false);
    return fmaxf(x, __int_as_float(r));
}
__device__ __forceinline__ float dpp_sum64(float x) {
    x = dpp_add_<0x111>(x);
    x = dpp_add_<0x112>(x);
    x = dpp_add_<0x114>(x);
    x = dpp_add_<0x118>(x);
    x = dpp_add_<0x142>(x);
    x = dpp_add_<0x143>(x);
    return __int_as_float(__builtin_amdgcn_readlane(__float_as_int(x), 63));
}
__device__ __forceinline__ float dpp_max64(float x) {
    x = dpp_max_<0x111>(x);
    x = dpp_max_<0x112>(x);
    x = dpp_max_<0x114>(x);
    x = dpp_max_<0x118>(x);
    x = dpp_max_<0x142>(x);
    x = dpp_max_<0x143>(x);
    return __int_as_float(__builtin_amdgcn_readlane(__float_as_int(x), 63));
}

// ============================ Kernel 1: dense phase (MFMA) ============================
// (unchanged from round 18)
__global__ __launch_bounds__(256, 2)
void dense_kernel(const float* __restrict__ content,   // [B,16,64]
                  const float* __restrict__ types,     // [B,16,3]
                  const float* __restrict__ conf,      // [B,16]
                  const float* __restrict__ W_ante,    // [64,64]
                  const float* __restrict__ W_cons,    // [64,128]
                  const float* __restrict__ W_gw,      // [64,128]
                  const float* __restrict__ lft,       // [1]
                  float* __restrict__ out, int B)
{
    const int tid = threadIdx.x;
    const int l = tid & 63;
    const int w = tid >> 6;
    const int b = blockIdx.x * 4 + w;

    __shared__ float s_cont[4][16*68];   // content rows
    __shared__ float s_scr [4][16*68];   // ante -> matched -> nf rows
    __shared__ float s_ms  [4][16*20];   // match_scores
    __shared__ float s_sm  [4][96];      // conf@0 pf@16 pr@32 rcn@48 ran@64
    __shared__ bs8   s_bA[512];          // B-frags: W_ante
    __shared__ bs8   s_b1[512];          // B-frags: W_cons[:, 0:64]
    __shared__ bs8   s_b2[512];          // B-frags: W_cons[:,64:128]
    __shared__ bs8   s_bG[512];          // B-frags: W_gw [:,64:128]

    // -------- cooperative B-fragment pack (once per block), 4 matrices --------
    #pragma unroll
    for (int it = 0; it < 8; it++) {
        const int fid = tid + it*256;           // 0..2047
        const int mat = fid >> 9, rem = fid & 511;
        const int fl  = rem & 63;
        const int row = ((rem >> 7) & 3)*16 + (fl & 15);
        const int kb  = ((rem >> 6) & 1)*32 + (fl >> 4)*8;
        const float* src = (mat == 0) ? (W_ante + row*64 + kb)
                         : (mat == 1) ? (W_cons + row*128 + kb)
                         : (mat == 2) ? (W_cons + row*128 + 64 + kb)
                         :              (W_gw  + row*128 + 64 + kb);
        bs8 v;
        #pragma unroll
        for (int e = 0; e < 8; e++) v[e] = bf16rne_(src[e]);
        bs8* dst = (mat == 0) ? s_bA : (mat == 1) ? s_b1 : (mat == 2) ? s_b2 : s_bG;
        dst[rem] = v;
    }
    __syncthreads();
    if (b >= B) return;

    float* cont = s_cont[w];
    float* scr  = s_scr[w];
    float* ms   = s_ms[w];
    float* sm   = s_sm[w];

    const float thr = expf(lft[0]);

    float c[16];
    const float* cb = content + ((size_t)b << 10);
    #pragma unroll
    for (int k = 0; k < 16; k++) {
        float v = cb[(k << 6) + l];
        c[k] = v;
        cont[k*68 + l] = v;
    }
    if (l < 16) {
        sm[0  + l] = conf[((size_t)b << 4) + l];
        sm[16 + l] = types[(((size_t)b << 4) + l)*3 + 0];   // p_fact
        sm[32 + l] = types[(((size_t)b << 4) + l)*3 + 1];   // p_rule
    }

    // content inverse norms -> sm[48+k]
    {
        const int k = l & 15, q = l >> 4;
        const v4f* row = (const v4f*)&cont[k*68 + q*16];
        v2f s2 = {0.f, 0.f};
        #pragma unroll
        for (int i = 0; i < 4; i++) { v4f v = row[i]; pk4(s2, v, v); }
        float s = hsum(s2);
        s += __shfl_xor(s, 16, 64);
        s += __shfl_xor(s, 32, 64);
        if (l < 16) sm[48 + l] = rsq_(s);
    }

    // A-fragments for content
    bs8 aC[2];
    #pragma unroll
    for (int s = 0; s < 2; s++) {
        const float* ap = &cont[(l & 15)*68 + s*32 + (l >> 4)*8];
        v4f p0 = *(const v4f*)ap;
        v4f p1 = *(const v4f*)(ap + 4);
        bs8 v;
        v[0]=bf16rne_(p0.x); v[1]=bf16rne_(p0.y); v[2]=bf16rne_(p0.z); v[3]=bf16rne_(p0.w);
        v[4]=bf16rne_(p1.x); v[5]=bf16rne_(p1.y); v[6]=bf16rne_(p1.z); v[7]=bf16rne_(p1.w);
        aC[s] = v;
    }

    // ---- ante = content @ W_ante^T via MFMA ----
    #pragma unroll
    for (int t = 0; t < 4; t++) {
        v4f acc = {0.f, 0.f, 0.f, 0.f};
        acc = __builtin_amdgcn_mfma_f32_16x16x32_bf16(aC[0], s_bA[(t*2+0)*64 + l], acc, 0, 0, 0);
        acc = __builtin_amdgcn_mfma_f32_16x16x32_bf16(aC[1], s_bA[(t*2+1)*64 + l], acc, 0, 0, 0);
        #pragma unroll
        for (int r = 0; r < 4; r++)
            scr[((l >> 4)*4 + r)*68 + t*16 + (l & 15)] = acc[r];
    }

    // ante inverse norms -> sm[64+k]
    {
        const int k = l & 15, q = l >> 4;
        const v4f* row = (const v4f*)&scr[k*68 + q*16];
        v2f s2 = {0.f, 0.f};
        #pragma unroll
        for (int i = 0; i < 4; i++) { v4f v = row[i]; pk4(s2, v, v); }
        float s = hsum(s2);
        s += __shfl_xor(s, 16, 64);
        s += __shfl_xor(s, 32, 64);
        if (l < 16) sm[64 + l] = rsq_(s);
    }

    // dots + match_scores (exact f32)
    {
        const int k = l & 15, jg4 = (l >> 4) * 4;
        const v4f* ar = (const v4f*)&scr[k*68];
        const v4f* c0 = (const v4f*)&cont[(jg4+0)*68];
        const v4f* c1 = (const v4f*)&cont[(jg4+1)*68];
        const v4f* c2 = (const v4f*)&cont[(jg4+2)*68];
        const v4f* c3 = (const v4f*)&cont[(jg4+3)*68];
        v2f d0 = {0,0}, d1 = {0,0}, d2 = {0,0}, d3 = {0,0};
        #pragma unroll
        for (int i = 0; i < 16; i++) {
            v4f a = ar[i];
            v4f x0 = c0[i]; d0 += a.xy*x0.xy; d0 += a.zw*x0.zw;
            v4f x1 = c1[i]; d1 += a.xy*x1.xy; d1 += a.zw*x1.zw;
            v4f x2 = c2[i]; d2 += a.xy*x2.xy; d2 += a.zw*x2.zw;
            v4f x3 = c3[i]; d3 += a.xy*x3.xy; d3 += a.zw*x3.zw;
        }
        const float ra = sm[64 + k];
        v4f res;
        res.x = hsum(d0) * ra * sm[48 + jg4+0] * sm[16 + jg4+0];
        res.y = hsum(d1) * ra * sm[48 + jg4+1] * sm[16 + jg4+1];
        res.z = hsum(d2) * ra * sm[48 + jg4+2] * sm[16 + jg4+2];
        res.w = hsum(d3) * ra * sm[48 + jg4+3] * sm[16 + jg4+3];
        *(v4f*)&ms[k*20 + jg4] = res;
    }

    // match_strength -> fire / dconf (lanes 0..15) -> staging + tail
    float dc_l = 0.f;
    if (l < 16) {
        const v4f* mr = (const v4f*)&ms[l*20];
        const v4f* cf = (const v4f*)&sm[0];
        v2f st = {0.f, 0.f};
        #pragma unroll
        for (int i = 0; i < 4; i++) { v4f m4 = mr[i]; v4f f4 = cf[i]; st += m4.xy*f4.xy; st += m4.zw*f4.zw; }
        float str = hsum(st);
        float fire = sm[32 + l] * rcp_(1.0f + __expf(-(str - thr) * 2.0f));
        float dcf  = fire * sm[0 + l];
        out[((size_t)b << 11) + 1024 + l] = fire;
        out[((size_t)b << 11) + 1040 + l] = dcf;
        dc_l = dcf;
    }
    {
        float mv = dc_l;
        mv = fmaxf(mv, __shfl_xor(mv, 1, 64));
        mv = fmaxf(mv, __shfl_xor(mv, 2, 64));
        mv = fmaxf(mv, __shfl_xor(mv, 4, 64));
        mv = fmaxf(mv, __shfl_xor(mv, 8, 64));
        if (l == 0) out[((size_t)B << 11) + b] = mv;
    }

    // matched[k][d] (exact f32, from regs c[])
    float mt[16];
    #pragma unroll
    for (int k = 0; k < 16; k++) {
        const v4f* mr = (const v4f*)&ms[k*20];
        v2f m2 = {0.f, 0.f};
        #pragma unroll
        for (int i = 0; i < 4; i++) {
            v4f m4 = mr[i];
            v2f clo = {c[4*i+0], c[4*i+1]};
            v2f chi = {c[4*i+2], c[4*i+3]};
            m2 += m4.xy*clo; m2 += m4.zw*chi;
        }
        mt[k] = hsum(m2);
    }
    #pragma unroll
    for (int k = 0; k < 16; k++) scr[k*68 + l] = mt[k];   // ante dead -> matched

    // A-fragments for matched
    bs8 aM[2];
    #pragma unroll
    for (int s = 0; s < 2; s++) {
        const float* ap = &scr[(l & 15)*68 + s*32 + (l >> 4)*8];
        v4f p0 = *(const v4f*)ap;
        v4f p1 = *(const v4f*)(ap + 4);
        bs8 v;
        v[0]=bf16rne_(p0.x); v[1]=bf16rne_(p0.y); v[2]=bf16rne_(p0.z); v[3]=bf16rne_(p0.w);
        v[4]=bf16rne_(p1.x); v[5]=bf16rne_(p1.y); v[6]=bf16rne_(p1.z); v[7]=bf16rne_(p1.w);
        aM[s] = v;
    }

    // ---- nf = content @ Wc1^T + matched @ Wc2^T via chained MFMA ----
    v4f nfacc[4];
    #pragma unroll
    for (int t = 0; t < 4; t++) {
        v4f acc = {0.f, 0.f, 0.f, 0.f};
        acc = __builtin_amdgcn_mfma_f32_16x16x32_bf16(aC[0], s_b1[(t*2+0)*64 + l], acc, 0, 0, 0);
        acc = __builtin_amdgcn_mfma_f32_16x16x32_bf16(aC[1], s_b1[(t*2+1)*64 + l], acc, 0, 0, 0);
        acc = __builtin_amdgcn_mfma_f32_16x16x32_bf16(aM[0], s_b2[(t*2+0)*64 + l], acc, 0, 0, 0);
        acc = __builtin_amdgcn_mfma_f32_16x16x32_bf16(aM[1], s_b2[(t*2+1)*64 + l], acc, 0, 0, 0);
        nfacc[t] = acc;
    }

    // nf -> scr rows (for gc A-frags) + global staging
    #pragma unroll
    for (int t = 0; t < 4; t++) {
        #pragma unroll
        for (int r = 0; r < 4; r++) {
            const int krow = (l >> 4)*4 + r, dcol = t*16 + (l & 15);
            scr[krow*68 + dcol] = nfacc[t][r];
            out[((size_t)b << 11) + (size_t)(krow << 6) + dcol] = nfacc[t][r];
        }
    }

    // 1/||cand|| from C-layout
    #pragma unroll
    for (int r = 0; r < 4; r++) {
        float s = 0.f;
        #pragma unroll
        for (int t = 0; t < 4; t++) s += nfacc[t][r]*nfacc[t][r];
        s += __shfl_xor(s, 1, 64);
        s += __shfl_xor(s, 2, 64);
        s += __shfl_xor(s, 4, 64);
        s += __shfl_xor(s, 8, 64);
        if ((l & 15) == 0)
            out[((size_t)b << 11) + 1056 + (l >> 4)*4 + r] = rsq_(s);
    }

    // A-fragments for nf (from scr rows)
    bs8 aN[2];
    #pragma unroll
    for (int s = 0; s < 2; s++) {
        const float* ap = &scr[(l & 15)*68 + s*32 + (l >> 4)*8];
        v4f p0 = *(const v4f*)ap;
        v4f p1 = *(const v4f*)(ap + 4);
        bs8 v;
        v[0]=bf16rne_(p0.x); v[1]=bf16rne_(p0.y); v[2]=bf16rne_(p0.z); v[3]=bf16rne_(p0.w);
        v[4]=bf16rne_(p1.x); v[5]=bf16rne_(p1.y); v[6]=bf16rne_(p1.z); v[7]=bf16rne_(p1.w);
        aN[s] = v;
    }

    // ---- gc = nf @ W_gw[:,64:]^T via MFMA -> bf16 staging ----
    unsigned short* gco = (unsigned short*)(out + ((size_t)b << 11) + 1088);
    #pragma unroll
    for (int t = 0; t < 4; t++) {
        v4f acc = {0.f, 0.f, 0.f, 0.f};
        acc = __builtin_amdgcn_mfma_f32_16x16x32_bf16(aN[0], s_bG[(t*2+0)*64 + l], acc, 0, 0, 0);
        acc = __builtin_amdgcn_mfma_f32_16x16x32_bf16(aN[1], s_bG[(t*2+1)*64 + l], acc, 0, 0, 0);
        #pragma unroll
        for (int r = 0; r < 4; r++)
            gco[(((l >> 4)*4 + r) << 6) + t*16 + (l & 15)] = (unsigned short)bf16rne_(acc[r]);
    }
}

// ============================ Kernel 2: sequential scan ============================
// 8 batches per block of 512 (1 wave each). S in regs (m,h) layout. gamma matvec
// on the (otherwise idle) MFMA pipe: A-rows replicated with bs so D[m][n]=gamma[n];
// lane l's own tile t=l>>4 holds gamma[l] -> no redistribution. W_gw[:,0:64]
// B-frags block-shared (8 KB). gc from global staging (off-chain).
__global__ __launch_bounds__(512, 4)
void scan_kernel(const float* __restrict__ Sg,      // [B,32,64]
                 const float* __restrict__ W_gw,    // [64,128]
                 const float* __restrict__ W_gb,    // [64]
                 float* __restrict__ out, int B)
{
    const int t = threadIdx.x;
    const int l = t & 63;
    const int w = t >> 6;                 // wave 0..7
    const int b = (blockIdx.x << 3) + w;  // batch

    __shared__ bs8   bG2[512];            // B-frags of W1 = W_gw[:,0:64]
    __shared__ float snf_  [8][16*64];    // new_fact rows (f32)
    __shared__ float smeta_[8][48];       // fire[16] dconf[16] 1/||cand||[16]
    __shared__ float bsb_  [8][68];       // best-slot row; overwritten with ncd in-place
    float* snf   = snf_[w];
    float* smeta = smeta_[w];
    float* bsb   = bsb_[w];

    const int m = l & 31, h = l >> 5;

    // block-cooperative W1 B-fragment pack (one frag per thread)
    {
        const int rem = t;                       // 0..511
        const int fl  = rem & 63;
        const int row = ((rem >> 7) & 3)*16 + (fl & 15);   // n
        const int kb  = ((rem >> 6) & 1)*32 + (fl >> 4)*8; // k
        const float* src = W_gw + (size_t)row*128 + kb;    // W1[n][k]
        bs8 v;
        #pragma unroll
        for (int e = 0; e < 8; e++) v[e] = bf16rne_(src[e]);
        bG2[rem] = v;
    }

    v2f Sreg[16];

    if (b < B) {
        if (l < 48) smeta[l] = out[((size_t)b << 11) + 1024 + l];

        const float* nfb = out + ((size_t)b << 11);
        #pragma unroll
        for (int i = 0; i < 4; i++) {
            *(v4f*)&snf[i*256 + l*4] = *(const v4f*)&nfb[i*256 + l*4];
        }

        const float* srow = Sg + ((size_t)b << 11) + (m << 6) + (h << 5);
        #pragma unroll
        for (int i = 0; i < 8; i++) {
            v4f v = *(const v4f*)&srow[i*4];
            Sreg[2*i]   = v.xy;
            Sreg[2*i+1] = v.zw;
        }
    }

    __syncthreads();          // bG2 visible to all waves
    if (b >= B) return;

    const unsigned short* gcg = (const unsigned short*)(out + ((size_t)b << 11) + 1088);
    const float gb = W_gb[l];
    const int q = l >> 4;     // my gamma tile

    #pragma unroll 1
    for (int k = 0; k < 16; k++) {
        const float fire = smeta[k];          // wave-uniform
        if (fire <= 0.1f) continue;
        const float dck  = smeta[16 + k];
        const float rncn = smeta[32 + k];     // 1/||cand||
        const unsigned short gcu = gcg[(k << 6) + l];   // early, off-chain
        const float cd   = snf[(k << 6) + l];

        // dot[m] = cand.S[m] and ||S[m]||^2 -- registers + broadcast cand
        v2f d2 = {0.f, 0.f}, n2 = {0.f, 0.f};
        {
            const v4f* cr = (const v4f*)&snf[(k << 6) + (h << 5)];
            #pragma unroll
            for (int i = 0; i < 8; i++) {
                v4f c = cr[i];
                d2 += Sreg[2*i]*c.xy;       d2 += Sreg[2*i+1]*c.zw;
                n2 += Sreg[2*i]*Sreg[2*i];  n2 += Sreg[2*i+1]*Sreg[2*i+1];
            }
        }
        float dt = hsum(d2);
        float nn = hsum(n2);
        dt += __shfl_xor(dt, 32, 64);
        nn += __shfl_xor(nn, 32, 64);
        const float sc = dt * rsq_(nn) * rncn;
        const float e  = __expf(4.0f * sc);

        // argmax via DPP max + ballot; first index on ties
        const float mx = dpp_max64(sc);
        const unsigned long long bal = __ballot(sc == mx);
        const int best = __ffsll(bal & 0xffffffffULL) - 1;   // wave-uniform

        // best-slot row -> bsb (owning 2 lanes write their halves)
        if (m == best) {
            #pragma unroll
            for (int j = 0; j < 8; j++) {
                v4f v = { Sreg[2*j].x, Sreg[2*j].y, Sreg[2*j+1].x, Sreg[2*j+1].y };
                *(v4f*)&bsb[(h << 5) + j*4] = v;
            }
        }

        // softmax sum via DPP; halves duplicated -> x2
        const float tot = dpp_sum64(e);
        const float wm  = dck * e * 2.0f * rcp_(tot);

        // ---- gamma via MFMA: A[m][k] = bs[k] (replicated rows) ----
        // lane's A-frag elems: bs[s*32 + (l>>4)*8 + e] -> 2 broadcast v4f reads/frag
        bs8 af[2];
        #pragma unroll
        for (int s = 0; s < 2; s++) {
            const float* bp = &bsb[s*32 + q*8];
            v4f p0 = *(const v4f*)bp;
            v4f p1 = *(const v4f*)(bp + 4);
            i4 pk;
            pk[0] = cvtpk_(p0.x, p0.y);
            pk[1] = cvtpk_(p0.z, p0.w);
            pk[2] = cvtpk_(p1.x, p1.y);
            pk[3] = cvtpk_(p1.z, p1.w);
            af[s] = __builtin_bit_cast(bs8, pk);
        }
        v4f g0 = {0,0,0,0}, g1 = {0,0,0,0}, g2a = {0,0,0,0}, g3 = {0,0,0,0};
        g0 = __builtin_amdgcn_mfma_f32_16x16x32_bf16(af[0], bG2[0*64 + l], g0, 0, 0, 0);
        g1 = __builtin_amdgcn_mfma_f32_16x16x32_bf16(af[0], bG2[2*64 + l], g1, 0, 0, 0);
        g2a = __builtin_amdgcn_mfma_f32_16x16x32_bf16(af[0], bG2[4*64 + l], g2a, 0, 0, 0);
        g3 = __builtin_amdgcn_mfma_f32_16x16x32_bf16(af[0], bG2[6*64 + l], g3, 0, 0, 0);
        g0 = __builtin_amdgcn_mfma_f32_16x16x32_bf16(af[1], bG2[1*64 + l], g0, 0, 0, 0);
        g1 = __builtin_amdgcn_mfma_f32_16x16x32_bf16(af[1], bG2[3*64 + l], g1, 0, 0, 0);
        g2a = __builtin_amdgcn_mfma_f32_16x16x32_bf16(af[1], bG2[5*64 + l], g2a, 0, 0, 0);
        g3 = __builtin_amdgcn_mfma_f32_16x16x32_bf16(af[1], bG2[7*64 + l], g3, 0, 0, 0);
        // lane l needs tile q=l>>4, any row-reg (all rows identical), col l&15
        const float gdot = (q < 2) ? ((q == 0) ? g0[0] : g1[0])
                                   : ((q == 2) ? g2a[0] : g3[0]);

        const float gck = bf2f_((short)gcu);
        const float g = gb + gck + gdot;
        const float gamma = rcp_(1.0f + __expf(-g));
        const float bsd = bsb[l];
        bsb[l] = gamma*cd + (1.0f - gamma)*bsd;   // ncd, in place (wave-ordered DS)

        // update own half-row: S[m][d] += wm * (ncd[d] - S[m][d])
        const v2f wm2 = {wm, wm};
        {
            const v4f* nr = (const v4f*)&bsb[h << 5];
            #pragma unroll
            for (int i = 0; i < 8; i++) {
                v4f nc = nr[i];
                Sreg[2*i]   += wm2 * (nc.xy - Sreg[2*i]);
                Sreg[2*i+1] += wm2 * (nc.zw - Sreg[2*i+1]);
            }
        }
    }

    // store S_new from regs (overwrites staging region)
    {
        float* ob = out + ((size_t)b << 11) + (m << 6) + (h << 5);
        #pragma unroll
        for (int j = 0; j < 8; j++) {
            v4f v = { Sreg[2*j].x, Sreg[2*j].y, Sreg[2*j+1].x, Sreg[2*j+1].y };
            *(v4f*)&ob[j*4] = v;
        }
    }
}

extern "C" void kernel_launch(void* const* d_in, const int* in_sizes, int n_in,
                              void* d_out, int out_size, void* d_ws, size_t ws_size,
                              hipStream_t stream) {
    const float* content = (const float*)d_in[0];
    const float* types   = (const float*)d_in[1];
    const float* conf    = (const float*)d_in[2];
    const float* S       = (const float*)d_in[3];
    const float* W_ante  = (const float*)d_in[4];
    const float* W_cons  = (const float*)d_in[5];
    const float* W_gw    = (const float*)d_in[6];
    const float* W_gb    = (const float*)d_in[7];
    const float* lft     = (const float*)d_in[8];

    const int B = in_sizes[0] / 1024;

    hipLaunchKernelGGL(dense_kernel, dim3((B + 3) / 4), dim3(256), 0, stream,
                       content, types, conf, W_ante, W_cons, W_gw, lft, (float*)d_out, B);
    hipLaunchKernelGGL(scan_kernel, dim3((B + 7) / 8), dim3(512), 0, stream,
                       S, W_gw, W_gb, (float*)d_out, B);
}

// Round 20
// 199.194 us; speedup vs baseline: 11.6423x; 1.0287x over previous
//
#include <hip/hip_runtime.h>
#include <math.h>

typedef float v2f __attribute__((ext_vector_type(2)));
typedef float v4f __attribute__((ext_vector_type(4)));
typedef short bs8 __attribute__((ext_vector_type(8)));   // 8 bf16 (4 VGPRs)
typedef int   i4  __attribute__((ext_vector_type(4)));

__device__ __forceinline__ float hsum(v2f a) { return a.x + a.y; }
__device__ __forceinline__ float rsq_(float x) { return __builtin_amdgcn_rsqf(fmaxf(x, 1e-16f)); }
__device__ __forceinline__ float rcp_(float x) { return __builtin_amdgcn_rcpf(x); }

__device__ __forceinline__ void pk4(v2f& acc, v4f a, v4f b) {
    acc += a.xy * b.xy;
    acc += a.zw * b.zw;
}

__device__ __forceinline__ short bf16rne_(float x) {
    unsigned u = __float_as_uint(x);
    return (short)((u + 0x7FFFu + ((u >> 16) & 1)) >> 16);
}
__device__ __forceinline__ float bf2f_(short s) {
    return __uint_as_float((unsigned)(unsigned short)s << 16);
}
// pack 2 f32 -> 1 u32 of 2 bf16 (RNE)
__device__ __forceinline__ int cvtpk_(float lo, float hi) {
    int r;
    asm("v_cvt_pk_bf16_f32 %0, %1, %2" : "=v"(r) : "v"(lo), "v"(hi));
    return r;
}
// x + x^32 across halves, pure VALU (no DS pipe): ret0[l]=x[32|(l&31)], ret1[l]=x[l&31]
__device__ __forceinline__ float xsum32_(float x) {
    auto r = __builtin_amdgcn_permlane32_swap(__float_as_int(x), __float_as_int(x), false, false);
    return __int_as_float(r[0]) + __int_as_float(r[1]);
}

// ---- DPP reductions over 32 slots (halves duplicated): 5 ops, result at lane 31.
template<int CTRL>
__device__ __forceinline__ float dpp_add_(float x) {
    int r = __builtin_amdgcn_update_dpp(0, __float_as_int(x), CTRL, 0xF, 0xF, true);
    return x + __int_as_float(r);
}
template<int CTRL>
__device__ __forceinline__ float dpp_max_(float x) {
    int r = __builtin_amdgcn_update_dpp(__float_as_int(x), __float_as_int(x), CTRL, 0xF, 0xF, false);
    return fmaxf(x, __int_as_float(r));
}
__device__ __forceinline__ float dpp_sum32h(float x) {
    x = dpp_add_<0x111>(x);   // row_shr:1
    x = dpp_add_<0x112>(x);   // row_shr:2
    x = dpp_add_<0x114>(x);   // row_shr:4
    x = dpp_add_<0x118>(x);   // row_shr:8
    x = dpp_add_<0x142>(x);   // row_bcast15 -> lane31 holds sum of lanes 0..31
    return __int_as_float(__builtin_amdgcn_readlane(__float_as_int(x), 31));
}
__device__ __forceinline__ float dpp_max32h(float x) {
    x = dpp_max_<0x111>(x);
    x = dpp_max_<0x112>(x);
    x = dpp_max_<0x114>(x);
    x = dpp_max_<0x118>(x);
    x = dpp_max_<0x142>(x);   // lane31 holds max of lanes 0..31
    return __int_as_float(__builtin_amdgcn_readlane(__float_as_int(x), 31));
}

// ============================ Kernel 1: dense phase (MFMA) ============================
// (unchanged from round 19)
__global__ __launch_bounds__(256, 2)
void dense_kernel(const float* __restrict__ content,   // [B,16,64]
                  const float* __restrict__ types,     // [B,16,3]
                  const float* __restrict__ conf,      // [B,16]
                  const float* __restrict__ W_ante,    // [64,64]
                  const float* __restrict__ W_cons,    // [64,128]
                  const float* __restrict__ W_gw,      // [64,128]
                  const float* __restrict__ lft,       // [1]
                  float* __restrict__ out, int B)
{
    const int tid = threadIdx.x;
    const int l = tid & 63;
    const int w = tid >> 6;
    const int b = blockIdx.x * 4 + w;

    __shared__ float s_cont[4][16*68];   // content rows
    __shared__ float s_scr [4][16*68];   // ante -> matched -> nf rows
    __shared__ float s_ms  [4][16*20];   // match_scores
    __shared__ float s_sm  [4][96];      // conf@0 pf@16 pr@32 rcn@48 ran@64
    __shared__ bs8   s_bA[512];          // B-frags: W_ante
    __shared__ bs8   s_b1[512];          // B-frags: W_cons[:, 0:64]
    __shared__ bs8   s_b2[512];          // B-frags: W_cons[:,64:128]
    __shared__ bs8   s_bG[512];          // B-frags: W_gw [:,64:128]

    #pragma unroll
    for (int it = 0; it < 8; it++) {
        const int fid = tid + it*256;           // 0..2047
        const int mat = fid >> 9, rem = fid & 511;
        const int fl  = rem & 63;
        const int row = ((rem >> 7) & 3)*16 + (fl & 15);
        const int kb  = ((rem >> 6) & 1)*32 + (fl >> 4)*8;
        const float* src = (mat == 0) ? (W_ante + row*64 + kb)
                         : (mat == 1) ? (W_cons + row*128 + kb)
                         : (mat == 2) ? (W_cons + row*128 + 64 + kb)
                         :              (W_gw  + row*128 + 64 + kb);
        bs8 v;
        #pragma unroll
        for (int e = 0; e < 8; e++) v[e] = bf16rne_(src[e]);
        bs8* dst = (mat == 0) ? s_bA : (mat == 1) ? s_b1 : (mat == 2) ? s_b2 : s_bG;
        dst[rem] = v;
    }
    __syncthreads();
    if (b >= B) return;

    float* cont = s_cont[w];
    float* scr  = s_scr[w];
    float* ms   = s_ms[w];
    float* sm   = s_sm[w];

    const float thr = expf(lft[0]);

    float c[16];
    const float* cb = content + ((size_t)b << 10);
    #pragma unroll
    for (int k = 0; k < 16; k++) {
        float v = cb[(k << 6) + l];
        c[k] = v;
        cont[k*68 + l] = v;
    }
    if (l < 16) {
        sm[0  + l] = conf[((size_t)b << 4) + l];
        sm[16 + l] = types[(((size_t)b << 4) + l)*3 + 0];   // p_fact
        sm[32 + l] = types[(((size_t)b << 4) + l)*3 + 1];   // p_rule
    }

    // content inverse norms -> sm[48+k]
    {
        const int k = l & 15, q = l >> 4;
        const v4f* row = (const v4f*)&cont[k*68 + q*16];
        v2f s2 = {0.f, 0.f};
        #pragma unroll
        for (int i = 0; i < 4; i++) { v4f v = row[i]; pk4(s2, v, v); }
        float s = hsum(s2);
        s += __shfl_xor(s, 16, 64);
        s += __shfl_xor(s, 32, 64);
        if (l < 16) sm[48 + l] = rsq_(s);
    }

    // A-fragments for content
    bs8 aC[2];
    #pragma unroll
    for (int s = 0; s < 2; s++) {
        const float* ap = &cont[(l & 15)*68 + s*32 + (l >> 4)*8];
        v4f p0 = *(const v4f*)ap;
        v4f p1 = *(const v4f*)(ap + 4);
        bs8 v;
        v[0]=bf16rne_(p0.x); v[1]=bf16rne_(p0.y); v[2]=bf16rne_(p0.z); v[3]=bf16rne_(p0.w);
        v[4]=bf16rne_(p1.x); v[5]=bf16rne_(p1.y); v[6]=bf16rne_(p1.z); v[7]=bf16rne_(p1.w);
        aC[s] = v;
    }

    // ---- ante = content @ W_ante^T via MFMA ----
    #pragma unroll
    for (int t = 0; t < 4; t++) {
        v4f acc = {0.f, 0.f, 0.f, 0.f};
        acc = __builtin_amdgcn_mfma_f32_16x16x32_bf16(aC[0], s_bA[(t*2+0)*64 + l], acc, 0, 0, 0);
        acc = __builtin_amdgcn_mfma_f32_16x16x32_bf16(aC[1], s_bA[(t*2+1)*64 + l], acc, 0, 0, 0);
        #pragma unroll
        for (int r = 0; r < 4; r++)
            scr[((l >> 4)*4 + r)*68 + t*16 + (l & 15)] = acc[r];
    }

    // ante inverse norms -> sm[64+k]
    {
        const int k = l & 15, q = l >> 4;
        const v4f* row = (const v4f*)&scr[k*68 + q*16];
        v2f s2 = {0.f, 0.f};
        #pragma unroll
        for (int i = 0; i < 4; i++) { v4f v = row[i]; pk4(s2, v, v); }
        float s = hsum(s2);
        s += __shfl_xor(s, 16, 64);
        s += __shfl_xor(s, 32, 64);
        if (l < 16) sm[64 + l] = rsq_(s);
    }

    // dots + match_scores (exact f32)
    {
        const int k = l & 15, jg4 = (l >> 4) * 4;
        const v4f* ar = (const v4f*)&scr[k*68];
        const v4f* c0 = (const v4f*)&cont[(jg4+0)*68];
        const v4f* c1 = (const v4f*)&cont[(jg4+1)*68];
        const v4f* c2 = (const v4f*)&cont[(jg4+2)*68];
        const v4f* c3 = (const v4f*)&cont[(jg4+3)*68];
        v2f d0 = {0,0}, d1 = {0,0}, d2 = {0,0}, d3 = {0,0};
        #pragma unroll
        for (int i = 0; i < 16; i++) {
            v4f a = ar[i];
            v4f x0 = c0[i]; d0 += a.xy*x0.xy; d0 += a.zw*x0.zw;
            v4f x1 = c1[i]; d1 += a.xy*x1.xy; d1 += a.zw*x1.zw;
            v4f x2 = c2[i]; d2 += a.xy*x2.xy; d2 += a.zw*x2.zw;
            v4f x3 = c3[i]; d3 += a.xy*x3.xy; d3 += a.zw*x3.zw;
        }
        const float ra = sm[64 + k];
        v4f res;
        res.x = hsum(d0) * ra * sm[48 + jg4+0] * sm[16 + jg4+0];
        res.y = hsum(d1) * ra * sm[48 + jg4+1] * sm[16 + jg4+1];
        res.z = hsum(d2) * ra * sm[48 + jg4+2] * sm[16 + jg4+2];
        res.w = hsum(d3) * ra * sm[48 + jg4+3] * sm[16 + jg4+3];
        *(v4f*)&ms[k*20 + jg4] = res;
    }

    // match_strength -> fire / dconf (lanes 0..15) -> staging + tail
    float dc_l = 0.f;
    if (l < 16) {
        const v4f* mr = (const v4f*)&ms[l*20];
        const v4f* cf = (const v4f*)&sm[0];
        v2f st = {0.f, 0.f};
        #pragma unroll
        for (int i = 0; i < 4; i++) { v4f m4 = mr[i]; v4f f4 = cf[i]; st += m4.xy*f4.xy; st += m4.zw*f4.zw; }
        float str = hsum(st);
        float fire = sm[32 + l] * rcp_(1.0f + __expf(-(str - thr) * 2.0f));
        float dcf  = fire * sm[0 + l];
        out[((size_t)b << 11) + 1024 + l] = fire;
        out[((size_t)b << 11) + 1040 + l] = dcf;
        dc_l = dcf;
    }
    {
        float mv = dc_l;
        mv = fmaxf(mv, __shfl_xor(mv, 1, 64));
        mv = fmaxf(mv, __shfl_xor(mv, 2, 64));
        mv = fmaxf(mv, __shfl_xor(mv, 4, 64));
        mv = fmaxf(mv, __shfl_xor(mv, 8, 64));
        if (l == 0) out[((size_t)B << 11) + b] = mv;
    }

    // matched[k][d] (exact f32, from regs c[])
    float mt[16];
    #pragma unroll
    for (int k = 0; k < 16; k++) {
        const v4f* mr = (const v4f*)&ms[k*20];
        v2f m2 = {0.f, 0.f};
        #pragma unroll
        for (int i = 0; i < 4; i++) {
            v4f m4 = mr[i];
            v2f clo = {c[4*i+0], c[4*i+1]};
            v2f chi = {c[4*i+2], c[4*i+3]};
            m2 += m4.xy*clo; m2 += m4.zw*chi;
        }
        mt[k] = hsum(m2);
    }
    #pragma unroll
    for (int k = 0; k < 16; k++) scr[k*68 + l] = mt[k];   // ante dead -> matched

    // A-fragments for matched
    bs8 aM[2];
    #pragma unroll
    for (int s = 0; s < 2; s++) {
        const float* ap = &scr[(l & 15)*68 + s*32 + (l >> 4)*8];
        v4f p0 = *(const v4f*)ap;
        v4f p1 = *(const v4f*)(ap + 4);
        bs8 v;
        v[0]=bf16rne_(p0.x); v[1]=bf16rne_(p0.y); v[2]=bf16rne_(p0.z); v[3]=bf16rne_(p0.w);
        v[4]=bf16rne_(p1.x); v[5]=bf16rne_(p1.y); v[6]=bf16rne_(p1.z); v[7]=bf16rne_(p1.w);
        aM[s] = v;
    }

    // ---- nf = content @ Wc1^T + matched @ Wc2^T via chained MFMA ----
    v4f nfacc[4];
    #pragma unroll
    for (int t = 0; t < 4; t++) {
        v4f acc = {0.f, 0.f, 0.f, 0.f};
        acc = __builtin_amdgcn_mfma_f32_16x16x32_bf16(aC[0], s_b1[(t*2+0)*64 + l], acc, 0, 0, 0);
        acc = __builtin_amdgcn_mfma_f32_16x16x32_bf16(aC[1], s_b1[(t*2+1)*64 + l], acc, 0, 0, 0);
        acc = __builtin_amdgcn_mfma_f32_16x16x32_bf16(aM[0], s_b2[(t*2+0)*64 + l], acc, 0, 0, 0);
        acc = __builtin_amdgcn_mfma_f32_16x16x32_bf16(aM[1], s_b2[(t*2+1)*64 + l], acc, 0, 0, 0);
        nfacc[t] = acc;
    }

    // nf -> scr rows (for gc A-frags) + global staging
    #pragma unroll
    for (int t = 0; t < 4; t++) {
        #pragma unroll
        for (int r = 0; r < 4; r++) {
            const int krow = (l >> 4)*4 + r, dcol = t*16 + (l & 15);
            scr[krow*68 + dcol] = nfacc[t][r];
            out[((size_t)b << 11) + (size_t)(krow << 6) + dcol] = nfacc[t][r];
        }
    }

    // 1/||cand|| from C-layout
    #pragma unroll
    for (int r = 0; r < 4; r++) {
        float s = 0.f;
        #pragma unroll
        for (int t = 0; t < 4; t++) s += nfacc[t][r]*nfacc[t][r];
        s += __shfl_xor(s, 1, 64);
        s += __shfl_xor(s, 2, 64);
        s += __shfl_xor(s, 4, 64);
        s += __shfl_xor(s, 8, 64);
        if ((l & 15) == 0)
            out[((size_t)b << 11) + 1056 + (l >> 4)*4 + r] = rsq_(s);
    }

    // A-fragments for nf (from scr rows)
    bs8 aN[2];
    #pragma unroll
    for (int s = 0; s < 2; s++) {
        const float* ap = &scr[(l & 15)*68 + s*32 + (l >> 4)*8];
        v4f p0 = *(const v4f*)ap;
        v4f p1 = *(const v4f*)(ap + 4);
        bs8 v;
        v[0]=bf16rne_(p0.x); v[1]=bf16rne_(p0.y); v[2]=bf16rne_(p0.z); v[3]=bf16rne_(p0.w);
        v[4]=bf16rne_(p1.x); v[5]=bf16rne_(p1.y); v[6]=bf16rne_(p1.z); v[7]=bf16rne_(p1.w);
        aN[s] = v;
    }

    // ---- gc = nf @ W_gw[:,64:]^T via MFMA -> bf16 staging ----
    unsigned short* gco = (unsigned short*)(out + ((size_t)b << 11) + 1088);
    #pragma unroll
    for (int t = 0; t < 4; t++) {
        v4f acc = {0.f, 0.f, 0.f, 0.f};
        acc = __builtin_amdgcn_mfma_f32_16x16x32_bf16(aN[0], s_bG[(t*2+0)*64 + l], acc, 0, 0, 0);
        acc = __builtin_amdgcn_mfma_f32_16x16x32_bf16(aN[1], s_bG[(t*2+1)*64 + l], acc, 0, 0, 0);
        #pragma unroll
        for (int r = 0; r < 4; r++)
            gco[(((l >> 4)*4 + r) << 6) + t*16 + (l & 15)] = (unsigned short)bf16rne_(acc[r]);
    }
}

// ============================ Kernel 2: sequential scan ============================
// 8 batches per block of 512 (1 wave each). S in regs (m,h) layout. gamma matvec
// on the MFMA pipe. Chain cuts: permlane32_swap (VALU) replaces ds_bpermute for
// the half combine; 5-op DPP reductions (32 slots, read lane 31); setprio around
// the MFMA cluster.
__global__ __launch_bounds__(512, 4)
void scan_kernel(const float* __restrict__ Sg,      // [B,32,64]
                 const float* __restrict__ W_gw,    // [64,128]
                 const float* __restrict__ W_gb,    // [64]
                 float* __restrict__ out, int B)
{
    const int t = threadIdx.x;
    const int l = t & 63;
    const int w = t >> 6;                 // wave 0..7
    const int b = (blockIdx.x << 3) + w;  // batch

    __shared__ bs8   bG2[512];            // B-frags of W1 = W_gw[:,0:64]
    __shared__ float snf_  [8][16*64];    // new_fact rows (f32)
    __shared__ float smeta_[8][48];       // fire[16] dconf[16] 1/||cand||[16]
    __shared__ float bsb_  [8][68];       // best-slot row; overwritten with ncd in-place
    float* snf   = snf_[w];
    float* smeta = smeta_[w];
    float* bsb   = bsb_[w];

    const int m = l & 31, h = l >> 5;

    // block-cooperative W1 B-fragment pack (one frag per thread)
    {
        const int rem = t;                       // 0..511
        const int fl  = rem & 63;
        const int row = ((rem >> 7) & 3)*16 + (fl & 15);   // n
        const int kb  = ((rem >> 6) & 1)*32 + (fl >> 4)*8; // k
        const float* src = W_gw + (size_t)row*128 + kb;    // W1[n][k]
        bs8 v;
        #pragma unroll
        for (int e = 0; e < 8; e++) v[e] = bf16rne_(src[e]);
        bG2[rem] = v;
    }

    v2f Sreg[16];

    if (b < B) {
        if (l < 48) smeta[l] = out[((size_t)b << 11) + 1024 + l];

        const float* nfb = out + ((size_t)b << 11);
        #pragma unroll
        for (int i = 0; i < 4; i++) {
            *(v4f*)&snf[i*256 + l*4] = *(const v4f*)&nfb[i*256 + l*4];
        }

        const float* srow = Sg + ((size_t)b << 11) + (m << 6) + (h << 5);
        #pragma unroll
        for (int i = 0; i < 8; i++) {
            v4f v = *(const v4f*)&srow[i*4];
            Sreg[2*i]   = v.xy;
            Sreg[2*i+1] = v.zw;
        }
    }

    __syncthreads();          // bG2 visible to all waves
    if (b >= B) return;

    const unsigned short* gcg = (const unsigned short*)(out + ((size_t)b << 11) + 1088);
    const float gb = W_gb[l];
    const int q = l >> 4;     // my gamma tile

    #pragma unroll 1
    for (int k = 0; k < 16; k++) {
        const float fire = smeta[k];          // wave-uniform
        if (fire <= 0.1f) continue;
        const float dck  = smeta[16 + k];
        const float rncn = smeta[32 + k];     // 1/||cand||
        const unsigned short gcu = gcg[(k << 6) + l];   // early, off-chain
        const float cd   = snf[(k << 6) + l];

        // dot[m] = cand.S[m] and ||S[m]||^2 -- registers + broadcast cand
        v2f d2 = {0.f, 0.f}, n2 = {0.f, 0.f};
        {
            const v4f* cr = (const v4f*)&snf[(k << 6) + (h << 5)];
            #pragma unroll
            for (int i = 0; i < 8; i++) {
                v4f c = cr[i];
                d2 += Sreg[2*i]*c.xy;       d2 += Sreg[2*i+1]*c.zw;
                n2 += Sreg[2*i]*Sreg[2*i];  n2 += Sreg[2*i+1]*Sreg[2*i+1];
            }
        }
        // combine half-rows on the VALU (permlane32_swap), not the DS pipe
        const float dt = xsum32_(hsum(d2));
        const float nn = xsum32_(hsum(n2));
        const float sc = dt * rsq_(nn) * rncn;
        const float e  = __expf(4.0f * sc);

        // argmax via 5-op DPP max + ballot; first index on ties
        const float mx = dpp_max32h(sc);
        const unsigned long long bal = __ballot(sc == mx);
        const int best = __ffsll(bal & 0xffffffffULL) - 1;   // wave-uniform

        // best-slot row -> bsb (owning 2 lanes write their halves)
        if (m == best) {
            #pragma unroll
            for (int j = 0; j < 8; j++) {
                v4f v = { Sreg[2*j].x, Sreg[2*j].y, Sreg[2*j+1].x, Sreg[2*j+1].y };
                *(v4f*)&bsb[(h << 5) + j*4] = v;
            }
        }

        // softmax sum via 5-op DPP (exact 32-slot sum -> no x2)
        const float tot = dpp_sum32h(e);
        const float wm  = dck * e * rcp_(tot);

        // ---- gamma via MFMA: A[m][k] = bs[k] (replicated rows) ----
        bs8 af[2];
        #pragma unroll
        for (int s = 0; s < 2; s++) {
            const float* bp = &bsb[s*32 + q*8];
            v4f p0 = *(const v4f*)bp;
            v4f p1 = *(const v4f*)(bp + 4);
            i4 pk;
            pk[0] = cvtpk_(p0.x, p0.y);
            pk[1] = cvtpk_(p0.z, p0.w);
            pk[2] = cvtpk_(p1.x, p1.y);
            pk[3] = cvtpk_(p1.z, p1.w);
            af[s] = __builtin_bit_cast(bs8, pk);
        }
        __builtin_amdgcn_s_setprio(1);
        v4f g0 = {0,0,0,0}, g1 = {0,0,0,0}, g2a = {0,0,0,0}, g3 = {0,0,0,0};
        g0 = __builtin_amdgcn_mfma_f32_16x16x32_bf16(af[0], bG2[0*64 + l], g0, 0, 0, 0);
        g1 = __builtin_amdgcn_mfma_f32_16x16x32_bf16(af[0], bG2[2*64 + l], g1, 0, 0, 0);
        g2a = __builtin_amdgcn_mfma_f32_16x16x32_bf16(af[0], bG2[4*64 + l], g2a, 0, 0, 0);
        g3 = __builtin_amdgcn_mfma_f32_16x16x32_bf16(af[0], bG2[6*64 + l], g3, 0, 0, 0);
        g0 = __builtin_amdgcn_mfma_f32_16x16x32_bf16(af[1], bG2[1*64 + l], g0, 0, 0, 0);
        g1 = __builtin_amdgcn_mfma_f32_16x16x32_bf16(af[1], bG2[3*64 + l], g1, 0, 0, 0);
        g2a = __builtin_amdgcn_mfma_f32_16x16x32_bf16(af[1], bG2[5*64 + l], g2a, 0, 0, 0);
        g3 = __builtin_amdgcn_mfma_f32_16x16x32_bf16(af[1], bG2[7*64 + l], g3, 0, 0, 0);
        __builtin_amdgcn_s_setprio(0);
        const float gdot = (q < 2) ? ((q == 0) ? g0[0] : g1[0])
                                   : ((q == 2) ? g2a[0] : g3[0]);

        const float gck = bf2f_((short)gcu);
        const float g = gb + gck + gdot;
        const float gamma = rcp_(1.0f + __expf(-g));
        const float bsd = bsb[l];
        bsb[l] = gamma*cd + (1.0f - gamma)*bsd;   // ncd, in place (wave-ordered DS)

        // update own half-row: S[m][d] += wm * (ncd[d] - S[m][d])
        const v2f wm2 = {wm, wm};
        {
            const v4f* nr = (const v4f*)&bsb[h << 5];
            #pragma unroll
            for (int i = 0; i < 8; i++) {
                v4f nc = nr[i];
                Sreg[2*i]   += wm2 * (nc.xy - Sreg[2*i]);
                Sreg[2*i+1] += wm2 * (nc.zw - Sreg[2*i+1]);
            }
        }
    }

    // store S_new from regs (overwrites staging region)
    {
        float* ob = out + ((size_t)b << 11) + (m << 6) + (h << 5);
        #pragma unroll
        for (int j = 0; j < 8; j++) {
            v4f v = { Sreg[2*j].x, Sreg[2*j].y, Sreg[2*j+1].x, Sreg[2*j+1].y };
            *(v4f*)&ob[j*4] = v;
        }
    }
}

extern "C" void kernel_launch(void* const* d_in, const int* in_sizes, int n_in,
                              void* d_out, int out_size, void* d_ws, size_t ws_size,
                              hipStream_t stream) {
    const float* content = (const float*)d_in[0];
    const float* types   = (const float*)d_in[1];
    const float* conf    = (const float*)d_in[2];
    const float* S       = (const float*)d_in[3];
    const float* W_ante  = (const float*)d_in[4];
    const float* W_cons  = (const float*)d_in[5];
    const float* W_gw    = (const float*)d_in[6];
    const float* W_gb    = (const float*)d_in[7];
    const float* lft     = (const float*)d_in[8];

    const int B = in_sizes[0] / 1024;

    hipLaunchKernelGGL(dense_kernel, dim3((B + 3) / 4), dim3(256), 0, stream,
                       content, types, conf, W_ante, W_cons, W_gw, lft, (float*)d_out, B);
    hipLaunchKernelGGL(scan_kernel, dim3((B + 7) / 8), dim3(512), 0, stream,
                       S, W_gw, W_gb, (float*)d_out, B);
}